// Round 1
// baseline (1997.293 us; speedup 1.0000x reference)
//
#include <hip/hip_runtime.h>
#include <hip/hip_bf16.h>

#define N_ 4
#define T_ 4096
#define D_ 512
#define H_ 8
#define DH_ 64
#define NH_ 4
#define NB_ 64
#define CS_ 256
#define L_ 16384

typedef unsigned short u16;
typedef unsigned int u32;

__device__ __forceinline__ u16 f2bf(float x){
    union { float f; u32 u; } c; c.f = x;
    u32 u = c.u;
    u32 r = (u + 0x7FFFu + ((u >> 16) & 1u)) >> 16;
    return (u16)r;
}
__device__ __forceinline__ float bf2f(u16 b){
    union { u32 u; float f; } c; c.u = ((u32)b) << 16;
    return c.f;
}

// ---------------------------------------------------------------------------
// K1: Q = x@W_Q + b_Q ; V = x@W_V + b_V   (fp32, 64x64 tiles, 4x4/thread)
// ---------------------------------------------------------------------------
__global__ __launch_bounds__(256) void k_qv(const float* __restrict__ x,
        const float* __restrict__ Wq, const float* __restrict__ bq,
        const float* __restrict__ Wv, const float* __restrict__ bv,
        float* __restrict__ Q, float* __restrict__ V){
    __shared__ float As[64][17];
    __shared__ float Bs[16][65];
    const int tid = threadIdx.x;
    const int tx = tid & 15, ty = tid >> 4;
    const int m0 = blockIdx.x * 64;
    const int cb = blockIdx.y;                 // 0..15 (0-7 -> Q, 8-15 -> V)
    const bool isQ = cb < 8;
    const float* W = isQ ? Wq : Wv;
    const int c0 = isQ ? cb * 64 : (cb - 8) * 64;
    float acc[4][4] = {};
    for (int kt = 0; kt < 512; kt += 16){
        #pragma unroll
        for (int i = 0; i < 4; ++i){
            int e = tid + i * 256;
            int m = e >> 4, kk = e & 15;
            As[m][kk] = x[(size_t)(m0 + m) * 512 + kt + kk];
        }
        #pragma unroll
        for (int i = 0; i < 4; ++i){
            int e = tid + i * 256;
            int kk = e >> 6, cc = e & 63;
            Bs[kk][cc] = W[(size_t)(kt + kk) * 512 + c0 + cc];
        }
        __syncthreads();
        #pragma unroll
        for (int kk = 0; kk < 16; ++kk){
            float a[4], b[4];
            #pragma unroll
            for (int i = 0; i < 4; ++i) a[i] = As[ty * 4 + i][kk];
            #pragma unroll
            for (int j = 0; j < 4; ++j) b[j] = Bs[kk][tx * 4 + j];
            #pragma unroll
            for (int i = 0; i < 4; ++i)
                #pragma unroll
                for (int j = 0; j < 4; ++j) acc[i][j] += a[i] * b[j];
        }
        __syncthreads();
    }
    const float* bias = isQ ? bq : bv;
    float* O = isQ ? Q : V;
    #pragma unroll
    for (int i = 0; i < 4; ++i){
        int m = m0 + ty * 4 + i;
        #pragma unroll
        for (int j = 0; j < 4; ++j){
            int c = c0 + tx * 4 + j;
            O[(size_t)m * 512 + c] = acc[i][j] + bias[c];
        }
    }
}

// ---------------------------------------------------------------------------
// K2: rotations + argmax -> buckets[h][n][j*T + t]  (fp32, exact tie rules)
// ---------------------------------------------------------------------------
__global__ __launch_bounds__(256) void k_rot(const float* __restrict__ Q,
        const float* __restrict__ rot, int* __restrict__ buckets){
    const int tb = blockIdx.x * 32;
    const int n = blockIdx.y, h = blockIdx.z;
    const int hn = h * N_ + n;
    __shared__ float Rs[64 * 128];
    __shared__ float Qs[32][64];
    const int tid = threadIdx.x;
    const float* rh = rot + (size_t)h * (64 * 128);   // [f][j][i] contiguous
    for (int i = tid; i < 8192; i += 256) Rs[i] = rh[i];
    for (int i = tid; i < 2048; i += 256){
        int t = i >> 6, f = i & 63;
        Qs[t][f] = Q[(size_t)(n * T_ + tb + t) * 512 + h * 64 + f];
    }
    __syncthreads();
    const int tx = tid & 31, tg = tid >> 5;   // tg: 8 groups of 4 t's
    float r[4][4] = {};
    for (int f = 0; f < 64; ++f){
        float q0 = Qs[tg * 4 + 0][f], q1 = Qs[tg * 4 + 1][f];
        float q2 = Qs[tg * 4 + 2][f], q3 = Qs[tg * 4 + 3][f];
        #pragma unroll
        for (int jj = 0; jj < 4; ++jj){
            float rv = Rs[f * 128 + jj * 32 + tx];
            r[0][jj] += q0 * rv; r[1][jj] += q1 * rv;
            r[2][jj] += q2 * rv; r[3][jj] += q3 * rv;
        }
    }
    #pragma unroll
    for (int tt = 0; tt < 4; ++tt){
        #pragma unroll
        for (int jj = 0; jj < 4; ++jj){
            // argmax over concat(r, -r); first-occurrence tie-break
            float bv = r[tt][jj]; int bi = tx;
            float nv = -bv;
            if (nv > bv){ bv = nv; bi = 32 + tx; }
            #pragma unroll
            for (int m = 16; m >= 1; m >>= 1){
                float ov = __shfl_xor(bv, m, 32);
                int   oi = __shfl_xor(bi, m, 32);
                if (ov > bv || (ov == bv && oi < bi)){ bv = ov; bi = oi; }
            }
            if (tx == 0){
                int t = tb + tg * 4 + tt;
                buckets[(size_t)hn * L_ + jj * T_ + t] = bi + jj * 64;
            }
        }
    }
}

// ---------------------------------------------------------------------------
// K3: stable counting sort per (h,n): sticker[pos] = item index, 256 bins
// ---------------------------------------------------------------------------
__global__ __launch_bounds__(256) void k_sort(const int* __restrict__ buckets,
        int* __restrict__ sticker){
    const int hn = blockIdx.x;
    const int* bk = buckets + (size_t)hn * L_;
    int* out = sticker + (size_t)hn * L_;
    __shared__ int hist[256];
    __shared__ int buf[4096];
    const int tid = threadIdx.x;
    hist[tid] = 0;
    __syncthreads();
    for (int i = tid; i < L_; i += 256) atomicAdd(&hist[bk[i]], 1);
    __syncthreads();
    int mycnt = hist[tid];
    for (int off = 1; off < 256; off <<= 1){
        int add = (tid >= off) ? hist[tid - off] : 0;
        __syncthreads();
        hist[tid] += add;
        __syncthreads();
    }
    int pos = hist[tid] - mycnt;   // exclusive start of my bucket
    __syncthreads();
    for (int base = 0; base < L_; base += 4096){
        for (int i = tid; i < 4096; i += 256) buf[i] = bk[base + i];
        __syncthreads();
        for (int k2 = 0; k2 < 4096; ++k2){
            if (buf[k2] == tid){ out[pos] = base + k2; ++pos; }
        }
        __syncthreads();
    }
}

// ---------------------------------------------------------------------------
// K4: chunked attention. block = (chunk c, n, h). 64 q x 128 k, DH=64
// ---------------------------------------------------------------------------
__global__ __launch_bounds__(256) void k_attn(const float* __restrict__ Q,
        const float* __restrict__ V, const int* __restrict__ buckets,
        const int* __restrict__ sticker, u16* __restrict__ o_hash,
        float* __restrict__ logit_hash){
    const int c = blockIdx.x, n = blockIdx.y, h = blockIdx.z;
    const int hn = h * N_ + n;
    const int tid = threadIdx.x;
    __shared__ int s_idx[128], s_buck[128], s_t[128];
    __shared__ float s_inv[128];
    __shared__ u16 s_ab[128][66];        // bf16 rows: first Q-raw, later V
    __shared__ float s_dots[64][129];
    __shared__ float s_lse[64];
    if (tid < 128){
        int cprev = (c + CS_ - 1) & (CS_ - 1);
        int pos = (tid < 64) ? c * 64 + tid : cprev * 64 + (tid - 64);
        int idx = sticker[(size_t)hn * L_ + pos];
        s_idx[tid] = idx;
        s_buck[tid] = buckets[(size_t)hn * L_ + idx];
        s_t[tid] = idx & (T_ - 1);
    }
    __syncthreads();
    // stage raw Q rows (queries = rows 0-63; keys also need rows 64-127), fp32 norms
    {
        const int lane = tid & 63, w = tid >> 6;
        for (int r0 = w; r0 < 128; r0 += 4){
            float v = Q[(size_t)(n * T_ + s_t[r0]) * 512 + h * 64 + lane];
            s_ab[r0][lane] = f2bf(v);
            float ss = v * v;
            #pragma unroll
            for (int m = 32; m >= 1; m >>= 1) ss += __shfl_xor(ss, m, 64);
            if (lane == 0) s_inv[r0] = 1.f / (sqrtf(ss) + 1e-6f);
        }
    }
    __syncthreads();
    const int tx = tid & 15, ty = tid >> 4;
    // dots: thread tile 4q x 8k
    {
        float acc[4][8] = {};
        for (int f = 0; f < 64; ++f){
            float a[4], b[8];
            #pragma unroll
            for (int i = 0; i < 4; ++i) a[i] = bf2f(s_ab[ty * 4 + i][f]);
            #pragma unroll
            for (int j = 0; j < 8; ++j) b[j] = bf2f(s_ab[tx * 8 + j][f]);
            #pragma unroll
            for (int i = 0; i < 4; ++i)
                #pragma unroll
                for (int j = 0; j < 8; ++j) acc[i][j] += a[i] * b[j];
        }
        #pragma unroll
        for (int i = 0; i < 4; ++i){
            int q = ty * 4 + i; int bq = s_buck[q]; int tq = s_t[q];
            #pragma unroll
            for (int j = 0; j < 8; ++j){
                int k = tx * 8 + j;
                float d = acc[i][j] * s_inv[k] * 0.125f;
                if (s_buck[k] != bq) d = -1e9f;     // bucket mask first
                if (s_t[k] == tq)   d = -1e-5f;     // self-overwrite second
                s_dots[q][k] = d;
            }
        }
    }
    __syncthreads();
    if (tid < 64){
        float m = -1e30f;
        for (int k = 0; k < 128; ++k) m = fmaxf(m, s_dots[tid][k]);
        float l = 0.f;
        for (int k = 0; k < 128; ++k) l += __expf(s_dots[tid][k] - m);
        s_lse[tid] = m + __logf(l);
    }
    __syncthreads();
    #pragma unroll
    for (int i = 0; i < 32; ++i){
        int e = tid + i * 256; int q = e >> 7, k = e & 127;
        s_dots[q][k] = __expf(s_dots[q][k] - s_lse[q]);
    }
    __syncthreads();
    // stage V rows (reuse s_ab)
    {
        const int lane = tid & 63, w = tid >> 6;
        for (int r0 = w; r0 < 128; r0 += 4){
            float v = V[(size_t)(n * T_ + s_t[r0]) * 512 + h * 64 + lane];
            s_ab[r0][lane] = f2bf(v);
        }
    }
    __syncthreads();
    // bo = probs @ V : thread tile 4q x 4d
    {
        float acc[4][4] = {};
        for (int k = 0; k < 128; ++k){
            float p[4], vv[4];
            #pragma unroll
            for (int i = 0; i < 4; ++i) p[i] = s_dots[ty * 4 + i][k];
            #pragma unroll
            for (int j = 0; j < 4; ++j) vv[j] = bf2f(s_ab[k][tx * 4 + j]);
            #pragma unroll
            for (int i = 0; i < 4; ++i)
                #pragma unroll
                for (int j = 0; j < 4; ++j) acc[i][j] += p[i] * vv[j];
        }
        #pragma unroll
        for (int i = 0; i < 4; ++i){
            int q = ty * 4 + i; int si = s_idx[q];
            int jj = si >> 12; int t = si & (T_ - 1);
            size_t base = ((size_t)(hn * NH_ + jj) * T_ + t) * 64;
            #pragma unroll
            for (int j = 0; j < 4; ++j) o_hash[base + tx * 4 + j] = f2bf(acc[i][j]);
        }
    }
    if (tid < 64){
        int si = s_idx[tid]; int jj = si >> 12; int t = si & (T_ - 1);
        logit_hash[(size_t)(hn * NH_ + jj) * T_ + t] = s_lse[tid];
    }
}

// ---------------------------------------------------------------------------
// K5: combine over NH hash rounds per head + fused LayerNorm. block = (t,n)
// ---------------------------------------------------------------------------
__global__ __launch_bounds__(256) void k_comb(const u16* __restrict__ o_hash,
        const float* __restrict__ logit_hash, const float* __restrict__ gamma,
        const float* __restrict__ beta, float* __restrict__ out){
    const int t = blockIdx.x, n = blockIdx.y;
    const int tid = threadIdx.x;
    __shared__ float s_pw[32];
    __shared__ float s_x[512];
    __shared__ float s_red[8];
    __shared__ float s_mu, s_rs;
    if (tid < 32){
        int h = tid >> 2, j = tid & 3;
        s_pw[tid] = logit_hash[(size_t)((h * N_ + n) * NH_ + j) * T_ + t];
    }
    __syncthreads();
    if (tid < 8){
        int h = tid;
        float m = -1e30f;
        #pragma unroll
        for (int j = 0; j < 4; ++j) m = fmaxf(m, s_pw[h * 4 + j]);
        float l = 0.f;
        #pragma unroll
        for (int j = 0; j < 4; ++j) l += __expf(s_pw[h * 4 + j] - m);
        float ls = m + __logf(l);
        #pragma unroll
        for (int j = 0; j < 4; ++j) s_pw[h * 4 + j] = __expf(s_pw[h * 4 + j] - ls);
    }
    __syncthreads();
    float va[2];
    #pragma unroll
    for (int i = 0; i < 2; ++i){
        int cidx = tid + i * 256;
        int h = cidx >> 6, d = cidx & 63;
        size_t base = (size_t)((h * N_ + n) * NH_) * T_ * 64;
        float acc = 0.f;
        #pragma unroll
        for (int j = 0; j < 4; ++j)
            acc += s_pw[h * 4 + j] * bf2f(o_hash[base + ((size_t)j * T_ + t) * 64 + d]);
        s_x[cidx] = acc; va[i] = acc;
    }
    float s1 = va[0] + va[1];
    float s2 = va[0] * va[0] + va[1] * va[1];
    #pragma unroll
    for (int m = 32; m >= 1; m >>= 1){
        s1 += __shfl_xor(s1, m, 64);
        s2 += __shfl_xor(s2, m, 64);
    }
    const int lane = tid & 63, w = tid >> 6;
    if (lane == 0){ s_red[w] = s1; s_red[4 + w] = s2; }
    __syncthreads();
    if (tid == 0){
        float S1 = s_red[0] + s_red[1] + s_red[2] + s_red[3];
        float S2 = s_red[4] + s_red[5] + s_red[6] + s_red[7];
        float mu = S1 / 512.f;
        float var = S2 / 512.f - mu * mu;
        s_mu = mu; s_rs = 1.f / sqrtf(var + 1e-3f);
    }
    __syncthreads();
    #pragma unroll
    for (int i = 0; i < 2; ++i){
        int cidx = tid + i * 256;
        out[((size_t)(n * T_ + t)) * 512 + cidx] =
            gamma[cidx] * (s_x[cidx] - s_mu) * s_rs + beta[cidx];
    }
}

// ---------------------------------------------------------------------------
extern "C" void kernel_launch(void* const* d_in, const int* in_sizes, int n_in,
                              void* d_out, int out_size, void* d_ws, size_t ws_size,
                              hipStream_t stream){
    const float* x     = (const float*)d_in[0];
    const float* Wq    = (const float*)d_in[1];
    const float* bq    = (const float*)d_in[2];
    const float* Wv    = (const float*)d_in[3];
    const float* bv    = (const float*)d_in[4];
    const float* gamma = (const float*)d_in[5];
    const float* beta  = (const float*)d_in[6];
    const float* rot   = (const float*)d_in[7];
    char* ws = (char*)d_ws;
    // workspace layout (total ~140.5 MB)
    float* Q        = (float*)(ws + 0);               // 33,554,432 B
    float* V        = (float*)(ws + 33554432);        // 33,554,432 B
    int*   buckets  = (int*)  (ws + 67108864);        //  2,097,152 B
    int*   sticker  = (int*)  (ws + 69206016);        //  2,097,152 B
    float* logit    = (float*)(ws + 71303168);        //  2,097,152 B
    u16*   o_hash   = (u16*)  (ws + 73400320);        // 67,108,864 B

    hipLaunchKernelGGL(k_qv,   dim3(256, 16),    dim3(256), 0, stream,
                       x, Wq, bq, Wv, bv, Q, V);
    hipLaunchKernelGGL(k_rot,  dim3(128, 4, 8),  dim3(256), 0, stream,
                       Q, rot, buckets);
    hipLaunchKernelGGL(k_sort, dim3(32),         dim3(256), 0, stream,
                       buckets, sticker);
    hipLaunchKernelGGL(k_attn, dim3(256, 4, 8),  dim3(256), 0, stream,
                       Q, V, buckets, sticker, o_hash, logit);
    hipLaunchKernelGGL(k_comb, dim3(4096, 4),    dim3(256), 0, stream,
                       o_hash, logit, gamma, beta, (float*)d_out);
}

// Round 2
// 992.158 us; speedup vs baseline: 2.0131x; 2.0131x over previous
//
#include <hip/hip_runtime.h>
#include <hip/hip_bf16.h>

#define N_ 4
#define T_ 4096
#define D_ 512
#define H_ 8
#define DH_ 64
#define NH_ 4
#define NB_ 64
#define CS_ 256
#define L_ 16384

typedef unsigned short u16;
typedef unsigned int u32;

__device__ __forceinline__ u16 f2bf(float x){
    union { float f; u32 u; } c; c.f = x;
    u32 u = c.u;
    u32 r = (u + 0x7FFFu + ((u >> 16) & 1u)) >> 16;
    return (u16)r;
}
__device__ __forceinline__ float bf2f(u16 b){
    union { u32 u; float f; } c; c.u = ((u32)b) << 16;
    return c.f;
}

// ---------------------------------------------------------------------------
// K1: Q = x@W_Q + b_Q ; V = x@W_V + b_V   (fp32, 64x64 tiles, 4x4/thread)
// ---------------------------------------------------------------------------
__global__ __launch_bounds__(256) void k_qv(const float* __restrict__ x,
        const float* __restrict__ Wq, const float* __restrict__ bq,
        const float* __restrict__ Wv, const float* __restrict__ bv,
        float* __restrict__ Q, float* __restrict__ V){
    __shared__ float As[64][17];
    __shared__ float Bs[16][65];
    const int tid = threadIdx.x;
    const int tx = tid & 15, ty = tid >> 4;
    const int m0 = blockIdx.x * 64;
    const int cb = blockIdx.y;                 // 0..15 (0-7 -> Q, 8-15 -> V)
    const bool isQ = cb < 8;
    const float* W = isQ ? Wq : Wv;
    const int c0 = isQ ? cb * 64 : (cb - 8) * 64;
    float acc[4][4] = {};
    for (int kt = 0; kt < 512; kt += 16){
        #pragma unroll
        for (int i = 0; i < 4; ++i){
            int e = tid + i * 256;
            int m = e >> 4, kk = e & 15;
            As[m][kk] = x[(size_t)(m0 + m) * 512 + kt + kk];
        }
        #pragma unroll
        for (int i = 0; i < 4; ++i){
            int e = tid + i * 256;
            int kk = e >> 6, cc = e & 63;
            Bs[kk][cc] = W[(size_t)(kt + kk) * 512 + c0 + cc];
        }
        __syncthreads();
        #pragma unroll
        for (int kk = 0; kk < 16; ++kk){
            float a[4], b[4];
            #pragma unroll
            for (int i = 0; i < 4; ++i) a[i] = As[ty * 4 + i][kk];
            #pragma unroll
            for (int j = 0; j < 4; ++j) b[j] = Bs[kk][tx * 4 + j];
            #pragma unroll
            for (int i = 0; i < 4; ++i)
                #pragma unroll
                for (int j = 0; j < 4; ++j) acc[i][j] += a[i] * b[j];
        }
        __syncthreads();
    }
    const float* bias = isQ ? bq : bv;
    float* O = isQ ? Q : V;
    #pragma unroll
    for (int i = 0; i < 4; ++i){
        int m = m0 + ty * 4 + i;
        #pragma unroll
        for (int j = 0; j < 4; ++j){
            int c = c0 + tx * 4 + j;
            O[(size_t)m * 512 + c] = acc[i][j] + bias[c];
        }
    }
}

// ---------------------------------------------------------------------------
// K2: rotations + argmax -> buckets[h][n][j*T + t]  (fp32, exact tie rules)
// ---------------------------------------------------------------------------
__global__ __launch_bounds__(256) void k_rot(const float* __restrict__ Q,
        const float* __restrict__ rot, int* __restrict__ buckets){
    const int tb = blockIdx.x * 32;
    const int n = blockIdx.y, h = blockIdx.z;
    const int hn = h * N_ + n;
    __shared__ float Rs[64 * 128];
    __shared__ float Qs[32][64];
    const int tid = threadIdx.x;
    const float* rh = rot + (size_t)h * (64 * 128);   // [f][j][i] contiguous
    for (int i = tid; i < 8192; i += 256) Rs[i] = rh[i];
    for (int i = tid; i < 2048; i += 256){
        int t = i >> 6, f = i & 63;
        Qs[t][f] = Q[(size_t)(n * T_ + tb + t) * 512 + h * 64 + f];
    }
    __syncthreads();
    const int tx = tid & 31, tg = tid >> 5;   // tg: 8 groups of 4 t's
    float r[4][4] = {};
    for (int f = 0; f < 64; ++f){
        float q0 = Qs[tg * 4 + 0][f], q1 = Qs[tg * 4 + 1][f];
        float q2 = Qs[tg * 4 + 2][f], q3 = Qs[tg * 4 + 3][f];
        #pragma unroll
        for (int jj = 0; jj < 4; ++jj){
            float rv = Rs[f * 128 + jj * 32 + tx];
            r[0][jj] += q0 * rv; r[1][jj] += q1 * rv;
            r[2][jj] += q2 * rv; r[3][jj] += q3 * rv;
        }
    }
    #pragma unroll
    for (int tt = 0; tt < 4; ++tt){
        #pragma unroll
        for (int jj = 0; jj < 4; ++jj){
            // argmax over concat(r, -r); first-occurrence tie-break
            float bv = r[tt][jj]; int bi = tx;
            float nv = -bv;
            if (nv > bv){ bv = nv; bi = 32 + tx; }
            #pragma unroll
            for (int m = 16; m >= 1; m >>= 1){
                float ov = __shfl_xor(bv, m, 32);
                int   oi = __shfl_xor(bi, m, 32);
                if (ov > bv || (ov == bv && oi < bi)){ bv = ov; bi = oi; }
            }
            if (tx == 0){
                int t = tb + tg * 4 + tt;
                buckets[(size_t)hn * L_ + jj * T_ + t] = bi + jj * 64;
            }
        }
    }
}

// ---------------------------------------------------------------------------
// K3a: per-(hn,tile) 256-bin histogram. tile = 256 consecutive items.
// ---------------------------------------------------------------------------
__global__ __launch_bounds__(256) void k_hist(const int* __restrict__ buckets,
        int* __restrict__ hist){
    const int tile = blockIdx.x, hn = blockIdx.y;
    const int tid = threadIdx.x;
    __shared__ int h[256];
    h[tid] = 0;
    __syncthreads();
    int b = buckets[(size_t)hn * L_ + tile * 256 + tid];
    atomicAdd(&h[b], 1);
    __syncthreads();
    hist[((size_t)hn * 64 + tile) * 256 + tid] = h[tid];
}

// ---------------------------------------------------------------------------
// K3b: per-hn: in-place exclusive prefix of hist over tiles (per bucket),
//      then block scan of bucket totals -> bucketStart[hn][256]
// ---------------------------------------------------------------------------
__global__ __launch_bounds__(256) void k_scan(int* __restrict__ hist,
        int* __restrict__ bucketStart){
    const int hn = blockIdx.x;
    const int b = threadIdx.x;
    int* hh = hist + (size_t)hn * 64 * 256;
    int run = 0;
    for (int tl = 0; tl < 64; ++tl){
        int v = hh[tl * 256 + b];
        hh[tl * 256 + b] = run;      // exclusive within-bucket tile prefix
        run += v;
    }
    __shared__ int s[256];
    s[b] = run;
    __syncthreads();
    for (int off = 1; off < 256; off <<= 1){
        int add = (b >= off) ? s[b - off] : 0;
        __syncthreads();
        s[b] += add;
        __syncthreads();
    }
    bucketStart[hn * 256 + b] = s[b] - run;   // exclusive bucket start
}

// ---------------------------------------------------------------------------
// K3c: stable scatter: sticker[pos] = item index
// ---------------------------------------------------------------------------
__global__ __launch_bounds__(256) void k_scatter(const int* __restrict__ buckets,
        const int* __restrict__ offs, const int* __restrict__ bucketStart,
        int* __restrict__ sticker){
    const int tile = blockIdx.x, hn = blockIdx.y;
    const int tid = threadIdx.x;
    __shared__ int sb[256];
    const int i = tile * 256 + tid;
    const int b = buckets[(size_t)hn * L_ + i];
    sb[tid] = b;
    __syncthreads();
    int rank = 0;
    #pragma unroll 8
    for (int j = 0; j < 256; ++j){
        int v = sb[j];                         // broadcast read
        rank += (j < tid && v == b) ? 1 : 0;
    }
    int pos = bucketStart[hn * 256 + b]
            + offs[((size_t)hn * 64 + tile) * 256 + b]
            + rank;
    sticker[(size_t)hn * L_ + pos] = i;
}

// ---------------------------------------------------------------------------
// K4: chunked attention. block = (chunk c, n, h). 64 q x 128 k, DH=64
// ---------------------------------------------------------------------------
__global__ __launch_bounds__(256) void k_attn(const float* __restrict__ Q,
        const float* __restrict__ V, const int* __restrict__ buckets,
        const int* __restrict__ sticker, u16* __restrict__ o_hash,
        float* __restrict__ logit_hash){
    const int c = blockIdx.x, n = blockIdx.y, h = blockIdx.z;
    const int hn = h * N_ + n;
    const int tid = threadIdx.x;
    __shared__ int s_idx[128], s_buck[128], s_t[128];
    __shared__ float s_inv[128];
    __shared__ u16 s_ab[128][66];        // bf16 rows: first Q-raw, later V
    __shared__ float s_dots[64][129];
    __shared__ float s_lse[64];
    if (tid < 128){
        int cprev = (c + CS_ - 1) & (CS_ - 1);
        int pos = (tid < 64) ? c * 64 + tid : cprev * 64 + (tid - 64);
        int idx = sticker[(size_t)hn * L_ + pos];
        s_idx[tid] = idx;
        s_buck[tid] = buckets[(size_t)hn * L_ + idx];
        s_t[tid] = idx & (T_ - 1);
    }
    __syncthreads();
    // stage raw Q rows (queries = rows 0-63; keys also need rows 64-127), fp32 norms
    {
        const int lane = tid & 63, w = tid >> 6;
        for (int r0 = w; r0 < 128; r0 += 4){
            float v = Q[(size_t)(n * T_ + s_t[r0]) * 512 + h * 64 + lane];
            s_ab[r0][lane] = f2bf(v);
            float ss = v * v;
            #pragma unroll
            for (int m = 32; m >= 1; m >>= 1) ss += __shfl_xor(ss, m, 64);
            if (lane == 0) s_inv[r0] = 1.f / (sqrtf(ss) + 1e-6f);
        }
    }
    __syncthreads();
    const int tx = tid & 15, ty = tid >> 4;
    // dots: thread tile 4q x 8k
    {
        float acc[4][8] = {};
        for (int f = 0; f < 64; ++f){
            float a[4], b[8];
            #pragma unroll
            for (int i = 0; i < 4; ++i) a[i] = bf2f(s_ab[ty * 4 + i][f]);
            #pragma unroll
            for (int j = 0; j < 8; ++j) b[j] = bf2f(s_ab[tx * 8 + j][f]);
            #pragma unroll
            for (int i = 0; i < 4; ++i)
                #pragma unroll
                for (int j = 0; j < 8; ++j) acc[i][j] += a[i] * b[j];
        }
        #pragma unroll
        for (int i = 0; i < 4; ++i){
            int q = ty * 4 + i; int bq = s_buck[q]; int tq = s_t[q];
            #pragma unroll
            for (int j = 0; j < 8; ++j){
                int k = tx * 8 + j;
                float d = acc[i][j] * s_inv[k] * 0.125f;
                if (s_buck[k] != bq) d = -1e9f;     // bucket mask first
                if (s_t[k] == tq)   d = -1e-5f;     // self-overwrite second
                s_dots[q][k] = d;
            }
        }
    }
    __syncthreads();
    if (tid < 64){
        float m = -1e30f;
        for (int k = 0; k < 128; ++k) m = fmaxf(m, s_dots[tid][k]);
        float l = 0.f;
        for (int k = 0; k < 128; ++k) l += __expf(s_dots[tid][k] - m);
        s_lse[tid] = m + __logf(l);
    }
    __syncthreads();
    #pragma unroll
    for (int i = 0; i < 32; ++i){
        int e = tid + i * 256; int q = e >> 7, k = e & 127;
        s_dots[q][k] = __expf(s_dots[q][k] - s_lse[q]);
    }
    __syncthreads();
    // stage V rows (reuse s_ab)
    {
        const int lane = tid & 63, w = tid >> 6;
        for (int r0 = w; r0 < 128; r0 += 4){
            float v = V[(size_t)(n * T_ + s_t[r0]) * 512 + h * 64 + lane];
            s_ab[r0][lane] = f2bf(v);
        }
    }
    __syncthreads();
    // bo = probs @ V : thread tile 4q x 4d
    {
        float acc[4][4] = {};
        for (int k = 0; k < 128; ++k){
            float p[4], vv[4];
            #pragma unroll
            for (int i = 0; i < 4; ++i) p[i] = s_dots[ty * 4 + i][k];
            #pragma unroll
            for (int j = 0; j < 4; ++j) vv[j] = bf2f(s_ab[k][tx * 4 + j]);
            #pragma unroll
            for (int i = 0; i < 4; ++i)
                #pragma unroll
                for (int j = 0; j < 4; ++j) acc[i][j] += p[i] * vv[j];
        }
        #pragma unroll
        for (int i = 0; i < 4; ++i){
            int q = ty * 4 + i; int si = s_idx[q];
            int jj = si >> 12; int t = si & (T_ - 1);
            size_t base = ((size_t)(hn * NH_ + jj) * T_ + t) * 64;
            #pragma unroll
            for (int j = 0; j < 4; ++j) o_hash[base + tx * 4 + j] = f2bf(acc[i][j]);
        }
    }
    if (tid < 64){
        int si = s_idx[tid]; int jj = si >> 12; int t = si & (T_ - 1);
        logit_hash[(size_t)(hn * NH_ + jj) * T_ + t] = s_lse[tid];
    }
}

// ---------------------------------------------------------------------------
// K5: combine over NH hash rounds per head + fused LayerNorm. block = (t,n)
// ---------------------------------------------------------------------------
__global__ __launch_bounds__(256) void k_comb(const u16* __restrict__ o_hash,
        const float* __restrict__ logit_hash, const float* __restrict__ gamma,
        const float* __restrict__ beta, float* __restrict__ out){
    const int t = blockIdx.x, n = blockIdx.y;
    const int tid = threadIdx.x;
    __shared__ float s_pw[32];
    __shared__ float s_x[512];
    __shared__ float s_red[8];
    __shared__ float s_mu, s_rs;
    if (tid < 32){
        int h = tid >> 2, j = tid & 3;
        s_pw[tid] = logit_hash[(size_t)((h * N_ + n) * NH_ + j) * T_ + t];
    }
    __syncthreads();
    if (tid < 8){
        int h = tid;
        float m = -1e30f;
        #pragma unroll
        for (int j = 0; j < 4; ++j) m = fmaxf(m, s_pw[h * 4 + j]);
        float l = 0.f;
        #pragma unroll
        for (int j = 0; j < 4; ++j) l += __expf(s_pw[h * 4 + j] - m);
        float ls = m + __logf(l);
        #pragma unroll
        for (int j = 0; j < 4; ++j) s_pw[h * 4 + j] = __expf(s_pw[h * 4 + j] - ls);
    }
    __syncthreads();
    float va[2];
    #pragma unroll
    for (int i = 0; i < 2; ++i){
        int cidx = tid + i * 256;
        int h = cidx >> 6, d = cidx & 63;
        size_t base = (size_t)((h * N_ + n) * NH_) * T_ * 64;
        float acc = 0.f;
        #pragma unroll
        for (int j = 0; j < 4; ++j)
            acc += s_pw[h * 4 + j] * bf2f(o_hash[base + ((size_t)j * T_ + t) * 64 + d]);
        s_x[cidx] = acc; va[i] = acc;
    }
    float s1 = va[0] + va[1];
    float s2 = va[0] * va[0] + va[1] * va[1];
    #pragma unroll
    for (int m = 32; m >= 1; m >>= 1){
        s1 += __shfl_xor(s1, m, 64);
        s2 += __shfl_xor(s2, m, 64);
    }
    const int lane = tid & 63, w = tid >> 6;
    if (lane == 0){ s_red[w] = s1; s_red[4 + w] = s2; }
    __syncthreads();
    if (tid == 0){
        float S1 = s_red[0] + s_red[1] + s_red[2] + s_red[3];
        float S2 = s_red[4] + s_red[5] + s_red[6] + s_red[7];
        float mu = S1 / 512.f;
        float var = S2 / 512.f - mu * mu;
        s_mu = mu; s_rs = 1.f / sqrtf(var + 1e-3f);
    }
    __syncthreads();
    #pragma unroll
    for (int i = 0; i < 2; ++i){
        int cidx = tid + i * 256;
        out[((size_t)(n * T_ + t)) * 512 + cidx] =
            gamma[cidx] * (s_x[cidx] - s_mu) * s_rs + beta[cidx];
    }
}

// ---------------------------------------------------------------------------
extern "C" void kernel_launch(void* const* d_in, const int* in_sizes, int n_in,
                              void* d_out, int out_size, void* d_ws, size_t ws_size,
                              hipStream_t stream){
    const float* x     = (const float*)d_in[0];
    const float* Wq    = (const float*)d_in[1];
    const float* bq    = (const float*)d_in[2];
    const float* Wv    = (const float*)d_in[3];
    const float* bv    = (const float*)d_in[4];
    const float* gamma = (const float*)d_in[5];
    const float* beta  = (const float*)d_in[6];
    const float* rot   = (const float*)d_in[7];
    char* ws = (char*)d_ws;
    // workspace layout (total ~140.5 MB)
    float* Q        = (float*)(ws + 0);               // 33,554,432 B
    float* V        = (float*)(ws + 33554432);        // 33,554,432 B
    int*   buckets  = (int*)  (ws + 67108864);        //  2,097,152 B
    int*   sticker  = (int*)  (ws + 69206016);        //  2,097,152 B
    float* logit    = (float*)(ws + 71303168);        //  2,097,152 B
    u16*   o_hash   = (u16*)  (ws + 73400320);        // 67,108,864 B
    // sort scratch overlaps o_hash (dead once k_scatter completes, and
    // o_hash is only written afterwards by k_attn — same stream, ordered):
    int*   hist     = (int*)  (ws + 73400320);        //  2,097,152 B (32*64*256)
    int*   bstart   = (int*)  (ws + 75497472);        //     32,768 B (32*256)

    hipLaunchKernelGGL(k_qv,      dim3(256, 16),    dim3(256), 0, stream,
                       x, Wq, bq, Wv, bv, Q, V);
    hipLaunchKernelGGL(k_rot,     dim3(128, 4, 8),  dim3(256), 0, stream,
                       Q, rot, buckets);
    hipLaunchKernelGGL(k_hist,    dim3(64, 32),     dim3(256), 0, stream,
                       buckets, hist);
    hipLaunchKernelGGL(k_scan,    dim3(32),         dim3(256), 0, stream,
                       hist, bstart);
    hipLaunchKernelGGL(k_scatter, dim3(64, 32),     dim3(256), 0, stream,
                       buckets, hist, bstart, sticker);
    hipLaunchKernelGGL(k_attn,    dim3(256, 4, 8),  dim3(256), 0, stream,
                       Q, V, buckets, sticker, o_hash, logit);
    hipLaunchKernelGGL(k_comb,    dim3(4096, 4),    dim3(256), 0, stream,
                       o_hash, logit, gamma, beta, (float*)d_out);
}

// Round 3
// 637.680 us; speedup vs baseline: 3.1321x; 1.5559x over previous
//
#include <hip/hip_runtime.h>
#include <hip/hip_bf16.h>

#define N_ 4
#define T_ 4096
#define D_ 512
#define H_ 8
#define DH_ 64
#define NH_ 4
#define NB_ 64
#define CS_ 256
#define L_ 16384

typedef unsigned short u16;
typedef unsigned int u32;
typedef __attribute__((ext_vector_type(8))) short short8;
typedef __attribute__((ext_vector_type(4))) float f32x4;

__device__ __forceinline__ u16 f2bf(float x){
    union { float f; u32 u; } c; c.f = x;
    u32 u = c.u;
    u32 r = (u + 0x7FFFu + ((u >> 16) & 1u)) >> 16;
    return (u16)r;
}
__device__ __forceinline__ float bf2f(u16 b){
    union { u32 u; float f; } c; c.u = ((u32)b) << 16;
    return c.f;
}

// ---------------------------------------------------------------------------
// K1: Q = x@W_Q + b_Q ; V = x@W_V + b_V   (fp32, 64x64 tiles, 4x4/thread)
// ---------------------------------------------------------------------------
__global__ __launch_bounds__(256) void k_qv(const float* __restrict__ x,
        const float* __restrict__ Wq, const float* __restrict__ bq,
        const float* __restrict__ Wv, const float* __restrict__ bv,
        float* __restrict__ Q, float* __restrict__ V){
    __shared__ float As[64][17];
    __shared__ float Bs[16][65];
    const int tid = threadIdx.x;
    const int tx = tid & 15, ty = tid >> 4;
    const int m0 = blockIdx.x * 64;
    const int cb = blockIdx.y;                 // 0..15 (0-7 -> Q, 8-15 -> V)
    const bool isQ = cb < 8;
    const float* W = isQ ? Wq : Wv;
    const int c0 = isQ ? cb * 64 : (cb - 8) * 64;
    float acc[4][4] = {};
    for (int kt = 0; kt < 512; kt += 16){
        #pragma unroll
        for (int i = 0; i < 4; ++i){
            int e = tid + i * 256;
            int m = e >> 4, kk = e & 15;
            As[m][kk] = x[(size_t)(m0 + m) * 512 + kt + kk];
        }
        #pragma unroll
        for (int i = 0; i < 4; ++i){
            int e = tid + i * 256;
            int kk = e >> 6, cc = e & 63;
            Bs[kk][cc] = W[(size_t)(kt + kk) * 512 + c0 + cc];
        }
        __syncthreads();
        #pragma unroll
        for (int kk = 0; kk < 16; ++kk){
            float a[4], b[4];
            #pragma unroll
            for (int i = 0; i < 4; ++i) a[i] = As[ty * 4 + i][kk];
            #pragma unroll
            for (int j = 0; j < 4; ++j) b[j] = Bs[kk][tx * 4 + j];
            #pragma unroll
            for (int i = 0; i < 4; ++i)
                #pragma unroll
                for (int j = 0; j < 4; ++j) acc[i][j] += a[i] * b[j];
        }
        __syncthreads();
    }
    const float* bias = isQ ? bq : bv;
    float* O = isQ ? Q : V;
    #pragma unroll
    for (int i = 0; i < 4; ++i){
        int m = m0 + ty * 4 + i;
        #pragma unroll
        for (int j = 0; j < 4; ++j){
            int c = c0 + tx * 4 + j;
            O[(size_t)m * 512 + c] = acc[i][j] + bias[c];
        }
    }
}

// ---------------------------------------------------------------------------
// K2: rotations + argmax -> buckets[h][n][j*T + t]  (fp32, exact tie rules)
// ---------------------------------------------------------------------------
__global__ __launch_bounds__(256) void k_rot(const float* __restrict__ Q,
        const float* __restrict__ rot, int* __restrict__ buckets){
    const int tb = blockIdx.x * 32;
    const int n = blockIdx.y, h = blockIdx.z;
    const int hn = h * N_ + n;
    __shared__ float Rs[64 * 128];
    __shared__ float Qs[32][64];
    const int tid = threadIdx.x;
    const float* rh = rot + (size_t)h * (64 * 128);   // [f][j][i] contiguous
    for (int i = tid; i < 8192; i += 256) Rs[i] = rh[i];
    for (int i = tid; i < 2048; i += 256){
        int t = i >> 6, f = i & 63;
        Qs[t][f] = Q[(size_t)(n * T_ + tb + t) * 512 + h * 64 + f];
    }
    __syncthreads();
    const int tx = tid & 31, tg = tid >> 5;   // tg: 8 groups of 4 t's
    float r[4][4] = {};
    for (int f = 0; f < 64; ++f){
        float q0 = Qs[tg * 4 + 0][f], q1 = Qs[tg * 4 + 1][f];
        float q2 = Qs[tg * 4 + 2][f], q3 = Qs[tg * 4 + 3][f];
        #pragma unroll
        for (int jj = 0; jj < 4; ++jj){
            float rv = Rs[f * 128 + jj * 32 + tx];
            r[0][jj] += q0 * rv; r[1][jj] += q1 * rv;
            r[2][jj] += q2 * rv; r[3][jj] += q3 * rv;
        }
    }
    #pragma unroll
    for (int tt = 0; tt < 4; ++tt){
        #pragma unroll
        for (int jj = 0; jj < 4; ++jj){
            // argmax over concat(r, -r); first-occurrence tie-break
            float bv = r[tt][jj]; int bi = tx;
            float nv = -bv;
            if (nv > bv){ bv = nv; bi = 32 + tx; }
            #pragma unroll
            for (int m = 16; m >= 1; m >>= 1){
                float ov = __shfl_xor(bv, m, 32);
                int   oi = __shfl_xor(bi, m, 32);
                if (ov > bv || (ov == bv && oi < bi)){ bv = ov; bi = oi; }
            }
            if (tx == 0){
                int t = tb + tg * 4 + tt;
                buckets[(size_t)hn * L_ + jj * T_ + t] = bi + jj * 64;
            }
        }
    }
}

// ---------------------------------------------------------------------------
// K3a: per-(hn,tile) 256-bin histogram. tile = 256 consecutive items.
// ---------------------------------------------------------------------------
__global__ __launch_bounds__(256) void k_hist(const int* __restrict__ buckets,
        int* __restrict__ hist){
    const int tile = blockIdx.x, hn = blockIdx.y;
    const int tid = threadIdx.x;
    __shared__ int h[256];
    h[tid] = 0;
    __syncthreads();
    int b = buckets[(size_t)hn * L_ + tile * 256 + tid];
    atomicAdd(&h[b], 1);
    __syncthreads();
    hist[((size_t)hn * 64 + tile) * 256 + tid] = h[tid];
}

// ---------------------------------------------------------------------------
// K3b: per-hn: in-place exclusive prefix of hist over tiles (per bucket),
//      then block scan of bucket totals -> bucketStart[hn][256]
// ---------------------------------------------------------------------------
__global__ __launch_bounds__(256) void k_scan(int* __restrict__ hist,
        int* __restrict__ bucketStart){
    const int hn = blockIdx.x;
    const int b = threadIdx.x;
    int* hh = hist + (size_t)hn * 64 * 256;
    int run = 0;
    for (int tl = 0; tl < 64; ++tl){
        int v = hh[tl * 256 + b];
        hh[tl * 256 + b] = run;      // exclusive within-bucket tile prefix
        run += v;
    }
    __shared__ int s[256];
    s[b] = run;
    __syncthreads();
    for (int off = 1; off < 256; off <<= 1){
        int add = (b >= off) ? s[b - off] : 0;
        __syncthreads();
        s[b] += add;
        __syncthreads();
    }
    bucketStart[hn * 256 + b] = s[b] - run;   // exclusive bucket start
}

// ---------------------------------------------------------------------------
// K3c: stable scatter: sticker[pos] = item index
// ---------------------------------------------------------------------------
__global__ __launch_bounds__(256) void k_scatter(const int* __restrict__ buckets,
        const int* __restrict__ offs, const int* __restrict__ bucketStart,
        int* __restrict__ sticker){
    const int tile = blockIdx.x, hn = blockIdx.y;
    const int tid = threadIdx.x;
    __shared__ int sb[256];
    const int i = tile * 256 + tid;
    const int b = buckets[(size_t)hn * L_ + i];
    sb[tid] = b;
    __syncthreads();
    int rank = 0;
    #pragma unroll 8
    for (int j = 0; j < 256; ++j){
        int v = sb[j];                         // broadcast read
        rank += (j < tid && v == b) ? 1 : 0;
    }
    int pos = bucketStart[hn * 256 + b]
            + offs[((size_t)hn * 64 + tile) * 256 + b]
            + rank;
    sticker[(size_t)hn * L_ + pos] = i;
}

// ---------------------------------------------------------------------------
// K4: chunked attention via MFMA. block = (chunk, n, h). 64 q x 128 k, DH=64
//     4 waves; wave w owns q-tile w (16 rows). bf16 fragments, fp32 softmax.
// ---------------------------------------------------------------------------
__global__ __launch_bounds__(256) void k_attn(const float* __restrict__ Q,
        const float* __restrict__ V, const int* __restrict__ buckets,
        const int* __restrict__ sticker, u16* __restrict__ o_hash,
        float* __restrict__ logit_hash){
    const int blk_c = blockIdx.x, n = blockIdx.y, h = blockIdx.z;
    const int hn = h * N_ + n;
    const int tid = threadIdx.x;
    const int w = tid >> 6, lane = tid & 63;
    const int quad = lane >> 4, cc = lane & 15;

    // XOR-swizzled bf16 tiles: element (r,c) of a 64-col tile lives at
    //   r*64 + ((c>>3)^(r&7))*8 + (c&7); 128-col tile uses ^(r&15).
    __shared__ __align__(16) u16 sQ[128 * 64];    // rows = sorted positions (raw Q)
    __shared__ __align__(16) u16 sVt[64 * 128];   // row = d, col = key row (V^T)
    __shared__ __align__(16) u16 sP[64 * 128];    // probs, row = q, col = k
    __shared__ int s_idx[128], s_buck[128], s_t[128];
    __shared__ float s_inv[128];
    __shared__ float s_lse[64];

    if (tid < 128){
        int cprev = (blk_c + CS_ - 1) & (CS_ - 1);
        int pos = (tid < 64) ? blk_c * 64 + tid : cprev * 64 + (tid - 64);
        int idx = sticker[(size_t)hn * L_ + pos];
        s_idx[tid] = idx;
        s_buck[tid] = buckets[(size_t)hn * L_ + idx];
        s_t[tid] = idx & (T_ - 1);
    }
    __syncthreads();

    // ---- stage Q rows (bf16, swizzled) + inv norms, and V transposed ----
    for (int pass = 0; pass < 8; ++pass){
        int r = pass * 16 + w * 4 + quad;
        int t = s_t[r];
        const float4* qp = (const float4*)&Q[(size_t)(n * T_ + t) * 512 + h * 64];
        float4 qv = qp[cc];
        int c0 = cc * 4;
        int physq = ((c0 >> 3) ^ (r & 7));
        u16* dst = &sQ[r * 64 + physq * 8 + (c0 & 7)];
        dst[0] = f2bf(qv.x); dst[1] = f2bf(qv.y);
        dst[2] = f2bf(qv.z); dst[3] = f2bf(qv.w);
        float ss = qv.x * qv.x + qv.y * qv.y + qv.z * qv.z + qv.w * qv.w;
        #pragma unroll
        for (int m = 8; m >= 1; m >>= 1) ss += __shfl_xor(ss, m, 64);
        if (cc == 0) s_inv[r] = 1.f / (sqrtf(ss) + 1e-6f);
        const float4* vp = (const float4*)&V[(size_t)(n * T_ + t) * 512 + h * 64];
        float4 vv = vp[cc];
        float ve[4] = {vv.x, vv.y, vv.z, vv.w};
        #pragma unroll
        for (int i = 0; i < 4; ++i){
            int d = c0 + i;
            sVt[d * 128 + (((r >> 3) ^ (d & 15)) * 8) + (r & 7)] = f2bf(ve[i]);
        }
    }
    __syncthreads();

    // ---- QK^T: wave w -> q-tile w; 2 k-chunks x 8 k-tiles ----
    f32x4 dacc[8];
    #pragma unroll
    for (int j = 0; j < 8; ++j) dacc[j] = (f32x4){0.f, 0.f, 0.f, 0.f};
    const int qrow = w * 16 + cc;
    #pragma unroll
    for (int kc = 0; kc < 2; ++kc){
        short8 afrag = *(const short8*)&sQ[qrow * 64 + (((kc * 4 + quad) ^ (cc & 7)) * 8)];
        #pragma unroll
        for (int kt = 0; kt < 8; ++kt){
            int krow = kt * 16 + cc;
            short8 bfrag = *(const short8*)&sQ[krow * 64 + (((kc * 4 + quad) ^ (cc & 7)) * 8)];
            dacc[kt] = __builtin_amdgcn_mfma_f32_16x16x32_bf16(afrag, bfrag, dacc[kt], 0, 0, 0);
        }
    }

    // ---- scale + masks + row softmax (rows: q = w*16 + quad*4 + reg) ----
    int bq[4], tq[4];
    #pragma unroll
    for (int r = 0; r < 4; ++r){
        int q = w * 16 + quad * 4 + r;
        bq[r] = s_buck[q]; tq[r] = s_t[q];
    }
    float mrow[4] = {-1e30f, -1e30f, -1e30f, -1e30f};
    #pragma unroll
    for (int kt = 0; kt < 8; ++kt){
        int kk = kt * 16 + cc;
        float inv = s_inv[kk] * 0.125f;
        int bk = s_buck[kk], tk = s_t[kk];
        #pragma unroll
        for (int r = 0; r < 4; ++r){
            float d = dacc[kt][r] * inv;
            if (bk != bq[r]) d = -1e9f;
            if (tk == tq[r]) d = -1e-5f;
            dacc[kt][r] = d;
            mrow[r] = fmaxf(mrow[r], d);
        }
    }
    #pragma unroll
    for (int r = 0; r < 4; ++r)
        #pragma unroll
        for (int m = 8; m >= 1; m >>= 1)
            mrow[r] = fmaxf(mrow[r], __shfl_xor(mrow[r], m, 64));
    float srow[4] = {0.f, 0.f, 0.f, 0.f};
    #pragma unroll
    for (int kt = 0; kt < 8; ++kt)
        #pragma unroll
        for (int r = 0; r < 4; ++r)
            srow[r] += __expf(dacc[kt][r] - mrow[r]);
    #pragma unroll
    for (int r = 0; r < 4; ++r)
        #pragma unroll
        for (int m = 8; m >= 1; m >>= 1)
            srow[r] += __shfl_xor(srow[r], m, 64);
    float lse[4];
    #pragma unroll
    for (int r = 0; r < 4; ++r) lse[r] = mrow[r] + __logf(srow[r]);
    if (cc == 0){
        #pragma unroll
        for (int r = 0; r < 4; ++r) s_lse[w * 16 + quad * 4 + r] = lse[r];
    }

    // ---- probs -> sP (C-layout scatter into swizzled A-layout tile) ----
    #pragma unroll
    for (int kt = 0; kt < 8; ++kt){
        int kk = kt * 16 + cc;
        #pragma unroll
        for (int r = 0; r < 4; ++r){
            int q = w * 16 + quad * 4 + r;
            sP[q * 128 + (((kk >> 3) ^ (q & 15)) * 8) + (kk & 7)] =
                f2bf(__expf(dacc[kt][r] - lse[r]));
        }
    }
    __syncthreads();

    // ---- PV: wave w -> q-tile w; 4 k-chunks x 4 n-tiles ----
    f32x4 oacc[4];
    #pragma unroll
    for (int j = 0; j < 4; ++j) oacc[j] = (f32x4){0.f, 0.f, 0.f, 0.f};
    #pragma unroll
    for (int kc = 0; kc < 4; ++kc){
        short8 afrag = *(const short8*)&sP[qrow * 128 + (((kc * 4 + quad) ^ cc) * 8)];
        #pragma unroll
        for (int nt = 0; nt < 4; ++nt){
            int d = nt * 16 + cc;
            short8 bfrag = *(const short8*)&sVt[d * 128 + (((kc * 4 + quad) ^ cc) * 8)];
            oacc[nt] = __builtin_amdgcn_mfma_f32_16x16x32_bf16(afrag, bfrag, oacc[nt], 0, 0, 0);
        }
    }

    // ---- epilogue: scatter o (bf16) and logits to per-hash buffers ----
    #pragma unroll
    for (int r = 0; r < 4; ++r){
        int q = w * 16 + quad * 4 + r;
        int si = s_idx[q];
        int jj = si >> 12; int t = si & (T_ - 1);
        size_t base = ((size_t)(hn * NH_ + jj) * T_ + t) * 64;
        #pragma unroll
        for (int nt = 0; nt < 4; ++nt)
            o_hash[base + nt * 16 + cc] = f2bf(oacc[nt][r]);
    }
    if (tid < 64){
        int si = s_idx[tid]; int jj = si >> 12; int t = si & (T_ - 1);
        logit_hash[(size_t)(hn * NH_ + jj) * T_ + t] = s_lse[tid];
    }
}

// ---------------------------------------------------------------------------
// K5: combine over NH hash rounds per head + fused LayerNorm. block = (t,n)
// ---------------------------------------------------------------------------
__global__ __launch_bounds__(256) void k_comb(const u16* __restrict__ o_hash,
        const float* __restrict__ logit_hash, const float* __restrict__ gamma,
        const float* __restrict__ beta, float* __restrict__ out){
    const int t = blockIdx.x, n = blockIdx.y;
    const int tid = threadIdx.x;
    __shared__ float s_pw[32];
    __shared__ float s_x[512];
    __shared__ float s_red[8];
    __shared__ float s_mu, s_rs;
    if (tid < 32){
        int h = tid >> 2, j = tid & 3;
        s_pw[tid] = logit_hash[(size_t)((h * N_ + n) * NH_ + j) * T_ + t];
    }
    __syncthreads();
    if (tid < 8){
        int h = tid;
        float m = -1e30f;
        #pragma unroll
        for (int j = 0; j < 4; ++j) m = fmaxf(m, s_pw[h * 4 + j]);
        float l = 0.f;
        #pragma unroll
        for (int j = 0; j < 4; ++j) l += __expf(s_pw[h * 4 + j] - m);
        float ls = m + __logf(l);
        #pragma unroll
        for (int j = 0; j < 4; ++j) s_pw[h * 4 + j] = __expf(s_pw[h * 4 + j] - ls);
    }
    __syncthreads();
    float va[2];
    #pragma unroll
    for (int i = 0; i < 2; ++i){
        int cidx = tid + i * 256;
        int h = cidx >> 6, d = cidx & 63;
        size_t base = (size_t)((h * N_ + n) * NH_) * T_ * 64;
        float acc = 0.f;
        #pragma unroll
        for (int j = 0; j < 4; ++j)
            acc += s_pw[h * 4 + j] * bf2f(o_hash[base + ((size_t)j * T_ + t) * 64 + d]);
        s_x[cidx] = acc; va[i] = acc;
    }
    float s1 = va[0] + va[1];
    float s2 = va[0] * va[0] + va[1] * va[1];
    #pragma unroll
    for (int m = 32; m >= 1; m >>= 1){
        s1 += __shfl_xor(s1, m, 64);
        s2 += __shfl_xor(s2, m, 64);
    }
    const int lane = tid & 63, w = tid >> 6;
    if (lane == 0){ s_red[w] = s1; s_red[4 + w] = s2; }
    __syncthreads();
    if (tid == 0){
        float S1 = s_red[0] + s_red[1] + s_red[2] + s_red[3];
        float S2 = s_red[4] + s_red[5] + s_red[6] + s_red[7];
        float mu = S1 / 512.f;
        float var = S2 / 512.f - mu * mu;
        s_mu = mu; s_rs = 1.f / sqrtf(var + 1e-3f);
    }
    __syncthreads();
    #pragma unroll
    for (int i = 0; i < 2; ++i){
        int cidx = tid + i * 256;
        out[((size_t)(n * T_ + t)) * 512 + cidx] =
            gamma[cidx] * (s_x[cidx] - s_mu) * s_rs + beta[cidx];
    }
}

// ---------------------------------------------------------------------------
extern "C" void kernel_launch(void* const* d_in, const int* in_sizes, int n_in,
                              void* d_out, int out_size, void* d_ws, size_t ws_size,
                              hipStream_t stream){
    const float* x     = (const float*)d_in[0];
    const float* Wq    = (const float*)d_in[1];
    const float* bq    = (const float*)d_in[2];
    const float* Wv    = (const float*)d_in[3];
    const float* bv    = (const float*)d_in[4];
    const float* gamma = (const float*)d_in[5];
    const float* beta  = (const float*)d_in[6];
    const float* rot   = (const float*)d_in[7];
    char* ws = (char*)d_ws;
    // workspace layout (total ~140.5 MB)
    float* Q        = (float*)(ws + 0);               // 33,554,432 B
    float* V        = (float*)(ws + 33554432);        // 33,554,432 B
    int*   buckets  = (int*)  (ws + 67108864);        //  2,097,152 B
    int*   sticker  = (int*)  (ws + 69206016);        //  2,097,152 B
    float* logit    = (float*)(ws + 71303168);        //  2,097,152 B
    u16*   o_hash   = (u16*)  (ws + 73400320);        // 67,108,864 B
    // sort scratch overlaps o_hash (dead once k_scatter completes, and
    // o_hash is only written afterwards by k_attn — same stream, ordered):
    int*   hist     = (int*)  (ws + 73400320);        //  2,097,152 B (32*64*256)
    int*   bstart   = (int*)  (ws + 75497472);        //     32,768 B (32*256)

    hipLaunchKernelGGL(k_qv,      dim3(256, 16),    dim3(256), 0, stream,
                       x, Wq, bq, Wv, bv, Q, V);
    hipLaunchKernelGGL(k_rot,     dim3(128, 4, 8),  dim3(256), 0, stream,
                       Q, rot, buckets);
    hipLaunchKernelGGL(k_hist,    dim3(64, 32),     dim3(256), 0, stream,
                       buckets, hist);
    hipLaunchKernelGGL(k_scan,    dim3(32),         dim3(256), 0, stream,
                       hist, bstart);
    hipLaunchKernelGGL(k_scatter, dim3(64, 32),     dim3(256), 0, stream,
                       buckets, hist, bstart, sticker);
    hipLaunchKernelGGL(k_attn,    dim3(256, 4, 8),  dim3(256), 0, stream,
                       Q, V, buckets, sticker, o_hash, logit);
    hipLaunchKernelGGL(k_comb,    dim3(4096, 4),    dim3(256), 0, stream,
                       o_hash, logit, gamma, beta, (float*)d_out);
}

// Round 5
// 458.836 us; speedup vs baseline: 4.3530x; 1.3898x over previous
//
#include <hip/hip_runtime.h>
#include <hip/hip_bf16.h>

#define N_ 4
#define T_ 4096
#define D_ 512
#define H_ 8
#define DH_ 64
#define NH_ 4
#define NB_ 64
#define CS_ 256
#define L_ 16384

typedef unsigned short u16;
typedef unsigned int u32;
typedef __attribute__((ext_vector_type(8))) short short8;
typedef __attribute__((ext_vector_type(8))) _Float16 half8;
typedef __attribute__((ext_vector_type(4))) float f32x4;

__device__ __forceinline__ u16 f2bf(float x){
    union { float f; u32 u; } c; c.f = x;
    u32 u = c.u;
    u32 r = (u + 0x7FFFu + ((u >> 16) & 1u)) >> 16;
    return (u16)r;
}
__device__ __forceinline__ float bf2f(u16 b){
    union { u32 u; float f; } c; c.u = ((u32)b) << 16;
    return c.f;
}
__device__ __forceinline__ u16 f2h(float x){
    _Float16 h = (_Float16)x;
    u16 r; __builtin_memcpy(&r, &h, 2); return r;
}

// ---------------------------------------------------------------------------
// K0a: x -> f16 copy (for V MFMA path)
// ---------------------------------------------------------------------------
__global__ __launch_bounds__(256) void k_decXf(const float* __restrict__ x,
        u16* __restrict__ xf){
    int i = blockIdx.x * 256 + threadIdx.x;        // float4 index
    float4 v = ((const float4*)x)[i];
    ushort4 o;
    o.x = f2h(v.x); o.y = f2h(v.y); o.z = f2h(v.z); o.w = f2h(v.w);
    ((ushort4*)xf)[i] = o;
}

// ---------------------------------------------------------------------------
// K0b: transpose Wv -> wvt [512 n][512 k] f16
// ---------------------------------------------------------------------------
__global__ __launch_bounds__(256) void k_decWv(const float* __restrict__ Wv,
        u16* __restrict__ wvt){
    __shared__ float tile[32][33];
    const int tid = threadIdx.x;
    const int kt = blockIdx.x * 32, nt = blockIdx.y * 32;
    const int tx = tid & 31, ty = tid >> 5;
    #pragma unroll
    for (int i = 0; i < 4; ++i)
        tile[ty + i * 8][tx] = Wv[(size_t)(kt + ty + i * 8) * 512 + nt + tx];
    __syncthreads();
    #pragma unroll
    for (int i = 0; i < 4; ++i){
        int n = ty + i * 8;
        wvt[(size_t)(nt + n) * 512 + kt + tx] = f2h(tile[tx][n]);
    }
}

// ---------------------------------------------------------------------------
// K1a: Q = x@W_Q + b_Q  (fp32 VALU — exact-class for bucket argmax).
//      128x64 block tile, 256 thr as 16x16, 8x4/thread, k-major A staging.
// ---------------------------------------------------------------------------
__global__ __launch_bounds__(256) void k_q(const float* __restrict__ x,
        const float* __restrict__ Wq, const float* __restrict__ bq,
        float* __restrict__ Q){
    __shared__ float sA[16][132];     // [k][m] transposed, pad 132
    __shared__ float sB[16][68];      // [k][n]
    const int tid = threadIdx.x;
    const int tx = tid & 15, ty = tid >> 4;
    const int mb = blockIdx.x * 128, nb = blockIdx.y * 64;
    float acc[8][4] = {};
    for (int k0 = 0; k0 < 512; k0 += 16){
        #pragma unroll
        for (int i = 0; i < 2; ++i){
            int idx = i * 256 + tid;               // 0..511
            int m = idx >> 2, kq = idx & 3;
            float4 v = *(const float4*)&x[(size_t)(mb + m) * 512 + k0 + kq * 4];
            sA[kq * 4 + 0][m] = v.x;
            sA[kq * 4 + 1][m] = v.y;
            sA[kq * 4 + 2][m] = v.z;
            sA[kq * 4 + 3][m] = v.w;
        }
        {
            int kk = tid >> 4, nq = tid & 15;
            *(float4*)&sB[kk][nq * 4] =
                *(const float4*)&Wq[(size_t)(k0 + kk) * 512 + nb + nq * 4];
        }
        __syncthreads();
        #pragma unroll
        for (int kk = 0; kk < 16; ++kk){
            float a[8], b[4];
            *(float4*)&a[0] = *(const float4*)&sA[kk][ty * 8];
            *(float4*)&a[4] = *(const float4*)&sA[kk][ty * 8 + 4];
            *(float4*)&b[0] = *(const float4*)&sB[kk][tx * 4];
            #pragma unroll
            for (int i = 0; i < 8; ++i)
                #pragma unroll
                for (int j = 0; j < 4; ++j) acc[i][j] += a[i] * b[j];
        }
        __syncthreads();
    }
    float4 bi = *(const float4*)&bq[nb + tx * 4];
    #pragma unroll
    for (int i = 0; i < 8; ++i){
        float4 o;
        o.x = acc[i][0] + bi.x; o.y = acc[i][1] + bi.y;
        o.z = acc[i][2] + bi.z; o.w = acc[i][3] + bi.w;
        *(float4*)&Q[(size_t)(mb + ty * 8 + i) * 512 + nb + tx * 4] = o;
    }
}

// ---------------------------------------------------------------------------
// K1b: V = x@W_V + b_V  via single-product f16 MFMA (V only feeds bf16 attn).
//      128x128 block, 4 waves x (4x4 tiles of 16x16x32), BK=32.
// ---------------------------------------------------------------------------
__global__ __launch_bounds__(256) void k_gemmV(const u16* __restrict__ xf,
        const u16* __restrict__ wvt, const float* __restrict__ bv,
        float* __restrict__ V){
    __shared__ __align__(16) u16 sA[128 * 40];
    __shared__ __align__(16) u16 sB[128 * 40];
    const int tid = threadIdx.x;
    const int mb = blockIdx.x * 128, nb = blockIdx.y * 128;
    const int w = tid >> 6, lane = tid & 63, quad = lane >> 4, cc = lane & 15;
    const int wm = (w & 1) * 64, wn = (w >> 1) * 64;
    f32x4 acc[4][4];
    #pragma unroll
    for (int i = 0; i < 4; ++i)
        #pragma unroll
        for (int j = 0; j < 4; ++j) acc[i][j] = (f32x4){0.f, 0.f, 0.f, 0.f};

    for (int k0 = 0; k0 < 512; k0 += 32){
        #pragma unroll
        for (int i = 0; i < 2; ++i){
            int idx = i * 256 + tid;               // 0..511
            int m = idx >> 2, ks = idx & 3;
            *(short8*)&sA[m * 40 + ks * 8] =
                *(const short8*)&xf[(size_t)(mb + m) * 512 + k0 + ks * 8];
            *(short8*)&sB[m * 40 + ks * 8] =
                *(const short8*)&wvt[(size_t)(nb + m) * 512 + k0 + ks * 8];
        }
        __syncthreads();
        half8 a[4], b[4];
        #pragma unroll
        for (int i = 0; i < 4; ++i){
            a[i] = *(const half8*)&sA[(wm + i * 16 + cc) * 40 + quad * 8];
            b[i] = *(const half8*)&sB[(wn + i * 16 + cc) * 40 + quad * 8];
        }
        #pragma unroll
        for (int i = 0; i < 4; ++i)
            #pragma unroll
            for (int j = 0; j < 4; ++j)
                acc[i][j] = __builtin_amdgcn_mfma_f32_16x16x32_f16(a[i], b[j], acc[i][j], 0, 0, 0);
        __syncthreads();
    }
    #pragma unroll
    for (int i = 0; i < 4; ++i)
        #pragma unroll
        for (int j = 0; j < 4; ++j){
            int c = nb + wn + j * 16 + cc;
            float bi = bv[c];
            #pragma unroll
            for (int r = 0; r < 4; ++r){
                int m = mb + wm + i * 16 + quad * 4 + r;
                V[(size_t)m * 512 + c] = acc[i][j][r] + bi;
            }
        }
}

// ---------------------------------------------------------------------------
// K2: rotations + argmax -> buckets[h][n][j*T + t]  (fp32, exact tie rules)
// ---------------------------------------------------------------------------
__global__ __launch_bounds__(256) void k_rot(const float* __restrict__ Q,
        const float* __restrict__ rot, int* __restrict__ buckets){
    const int tb = blockIdx.x * 32;
    const int n = blockIdx.y, h = blockIdx.z;
    const int hn = h * N_ + n;
    __shared__ float Rs[64 * 128];
    __shared__ float Qs[32][64];
    const int tid = threadIdx.x;
    const float* rh = rot + (size_t)h * (64 * 128);   // [f][j][i] contiguous
    for (int i = tid; i < 8192; i += 256) Rs[i] = rh[i];
    for (int i = tid; i < 2048; i += 256){
        int t = i >> 6, f = i & 63;
        Qs[t][f] = Q[(size_t)(n * T_ + tb + t) * 512 + h * 64 + f];
    }
    __syncthreads();
    const int tx = tid & 31, tg = tid >> 5;   // tg: 8 groups of 4 t's
    float r[4][4] = {};
    for (int f = 0; f < 64; ++f){
        float q0 = Qs[tg * 4 + 0][f], q1 = Qs[tg * 4 + 1][f];
        float q2 = Qs[tg * 4 + 2][f], q3 = Qs[tg * 4 + 3][f];
        #pragma unroll
        for (int jj = 0; jj < 4; ++jj){
            float rv = Rs[f * 128 + jj * 32 + tx];
            r[0][jj] += q0 * rv; r[1][jj] += q1 * rv;
            r[2][jj] += q2 * rv; r[3][jj] += q3 * rv;
        }
    }
    #pragma unroll
    for (int tt = 0; tt < 4; ++tt){
        #pragma unroll
        for (int jj = 0; jj < 4; ++jj){
            // argmax over concat(r, -r); first-occurrence tie-break
            float bv = r[tt][jj]; int bi = tx;
            float nv = -bv;
            if (nv > bv){ bv = nv; bi = 32 + tx; }
            #pragma unroll
            for (int m = 16; m >= 1; m >>= 1){
                float ov = __shfl_xor(bv, m, 32);
                int   oi = __shfl_xor(bi, m, 32);
                if (ov > bv || (ov == bv && oi < bi)){ bv = ov; bi = oi; }
            }
            if (tx == 0){
                int t = tb + tg * 4 + tt;
                buckets[(size_t)hn * L_ + jj * T_ + t] = bi + jj * 64;
            }
        }
    }
}

// ---------------------------------------------------------------------------
// K3a: per-(hn,tile) 256-bin histogram. tile = 256 consecutive items.
// ---------------------------------------------------------------------------
__global__ __launch_bounds__(256) void k_hist(const int* __restrict__ buckets,
        int* __restrict__ hist){
    const int tile = blockIdx.x, hn = blockIdx.y;
    const int tid = threadIdx.x;
    __shared__ int h[256];
    h[tid] = 0;
    __syncthreads();
    int b = buckets[(size_t)hn * L_ + tile * 256 + tid];
    atomicAdd(&h[b], 1);
    __syncthreads();
    hist[((size_t)hn * 64 + tile) * 256 + tid] = h[tid];
}

// ---------------------------------------------------------------------------
// K3b: per-hn: in-place exclusive prefix of hist over tiles (per bucket),
//      then block scan of bucket totals -> bucketStart[hn][256]
// ---------------------------------------------------------------------------
__global__ __launch_bounds__(256) void k_scan(int* __restrict__ hist,
        int* __restrict__ bucketStart){
    const int hn = blockIdx.x;
    const int b = threadIdx.x;
    int* hh = hist + (size_t)hn * 64 * 256;
    int run = 0;
    for (int tl = 0; tl < 64; ++tl){
        int v = hh[tl * 256 + b];
        hh[tl * 256 + b] = run;      // exclusive within-bucket tile prefix
        run += v;
    }
    __shared__ int s[256];
    s[b] = run;
    __syncthreads();
    for (int off = 1; off < 256; off <<= 1){
        int add = (b >= off) ? s[b - off] : 0;
        __syncthreads();
        s[b] += add;
        __syncthreads();
    }
    bucketStart[hn * 256 + b] = s[b] - run;   // exclusive bucket start
}

// ---------------------------------------------------------------------------
// K3c: stable scatter: sticker[pos] = item index
// ---------------------------------------------------------------------------
__global__ __launch_bounds__(256) void k_scatter(const int* __restrict__ buckets,
        const int* __restrict__ offs, const int* __restrict__ bucketStart,
        int* __restrict__ sticker){
    const int tile = blockIdx.x, hn = blockIdx.y;
    const int tid = threadIdx.x;
    __shared__ int sb[256];
    const int i = tile * 256 + tid;
    const int b = buckets[(size_t)hn * L_ + i];
    sb[tid] = b;
    __syncthreads();
    int rank = 0;
    #pragma unroll 8
    for (int j = 0; j < 256; ++j){
        int v = sb[j];                         // broadcast read
        rank += (j < tid && v == b) ? 1 : 0;
    }
    int pos = bucketStart[hn * 256 + b]
            + offs[((size_t)hn * 64 + tile) * 256 + b]
            + rank;
    sticker[(size_t)hn * L_ + pos] = i;
}

// ---------------------------------------------------------------------------
// K4: chunked attention via MFMA. block = (chunk, n, h). 64 q x 128 k, DH=64
//     4 waves; wave w owns q-tile w (16 rows). bf16 fragments, fp32 softmax.
// ---------------------------------------------------------------------------
__global__ __launch_bounds__(256) void k_attn(const float* __restrict__ Q,
        const float* __restrict__ V, const int* __restrict__ buckets,
        const int* __restrict__ sticker, u16* __restrict__ o_hash,
        float* __restrict__ logit_hash){
    const int blk_c = blockIdx.x, n = blockIdx.y, h = blockIdx.z;
    const int hn = h * N_ + n;
    const int tid = threadIdx.x;
    const int w = tid >> 6, lane = tid & 63;
    const int quad = lane >> 4, cc = lane & 15;

    // XOR-swizzled bf16 tiles: element (r,c) of a 64-col tile lives at
    //   r*64 + ((c>>3)^(r&7))*8 + (c&7); 128-col tile uses ^(r&15).
    __shared__ __align__(16) u16 sQ[128 * 64];    // rows = sorted positions (raw Q)
    __shared__ __align__(16) u16 sVt[64 * 128];   // row = d, col = key row (V^T)
    __shared__ __align__(16) u16 sP[64 * 128];    // probs, row = q, col = k
    __shared__ int s_idx[128], s_buck[128], s_t[128];
    __shared__ float s_inv[128];
    __shared__ float s_lse[64];

    if (tid < 128){
        int cprev = (blk_c + CS_ - 1) & (CS_ - 1);
        int pos = (tid < 64) ? blk_c * 64 + tid : cprev * 64 + (tid - 64);
        int idx = sticker[(size_t)hn * L_ + pos];
        s_idx[tid] = idx;
        s_buck[tid] = buckets[(size_t)hn * L_ + idx];
        s_t[tid] = idx & (T_ - 1);
    }
    __syncthreads();

    // ---- stage Q rows (bf16, swizzled) + inv norms, and V transposed ----
    for (int pass = 0; pass < 8; ++pass){
        int r = pass * 16 + w * 4 + quad;
        int t = s_t[r];
        const float4* qp = (const float4*)&Q[(size_t)(n * T_ + t) * 512 + h * 64];
        float4 qv = qp[cc];
        int c0 = cc * 4;
        int physq = ((c0 >> 3) ^ (r & 7));
        u16* dst = &sQ[r * 64 + physq * 8 + (c0 & 7)];
        dst[0] = f2bf(qv.x); dst[1] = f2bf(qv.y);
        dst[2] = f2bf(qv.z); dst[3] = f2bf(qv.w);
        float ss = qv.x * qv.x + qv.y * qv.y + qv.z * qv.z + qv.w * qv.w;
        #pragma unroll
        for (int m = 8; m >= 1; m >>= 1) ss += __shfl_xor(ss, m, 64);
        if (cc == 0) s_inv[r] = 1.f / (sqrtf(ss) + 1e-6f);
        const float4* vp = (const float4*)&V[(size_t)(n * T_ + t) * 512 + h * 64];
        float4 vv = vp[cc];
        float ve[4] = {vv.x, vv.y, vv.z, vv.w};
        #pragma unroll
        for (int i = 0; i < 4; ++i){
            int d = c0 + i;
            sVt[d * 128 + (((r >> 3) ^ (d & 15)) * 8) + (r & 7)] = f2bf(ve[i]);
        }
    }
    __syncthreads();

    // ---- QK^T: wave w -> q-tile w; 2 k-chunks x 8 k-tiles ----
    f32x4 dacc[8];
    #pragma unroll
    for (int j = 0; j < 8; ++j) dacc[j] = (f32x4){0.f, 0.f, 0.f, 0.f};
    const int qrow = w * 16 + cc;
    #pragma unroll
    for (int kc = 0; kc < 2; ++kc){
        short8 afrag = *(const short8*)&sQ[qrow * 64 + (((kc * 4 + quad) ^ (cc & 7)) * 8)];
        #pragma unroll
        for (int kt = 0; kt < 8; ++kt){
            int krow = kt * 16 + cc;
            short8 bfrag = *(const short8*)&sQ[krow * 64 + (((kc * 4 + quad) ^ (cc & 7)) * 8)];
            dacc[kt] = __builtin_amdgcn_mfma_f32_16x16x32_bf16(afrag, bfrag, dacc[kt], 0, 0, 0);
        }
    }

    // ---- scale + masks + row softmax (rows: q = w*16 + quad*4 + reg) ----
    int bq[4], tq[4];
    #pragma unroll
    for (int r = 0; r < 4; ++r){
        int q = w * 16 + quad * 4 + r;
        bq[r] = s_buck[q]; tq[r] = s_t[q];
    }
    float mrow[4] = {-1e30f, -1e30f, -1e30f, -1e30f};
    #pragma unroll
    for (int kt = 0; kt < 8; ++kt){
        int kk = kt * 16 + cc;
        float inv = s_inv[kk] * 0.125f;
        int bk = s_buck[kk], tk = s_t[kk];
        #pragma unroll
        for (int r = 0; r < 4; ++r){
            float d = dacc[kt][r] * inv;
            if (bk != bq[r]) d = -1e9f;
            if (tk == tq[r]) d = -1e-5f;
            dacc[kt][r] = d;
            mrow[r] = fmaxf(mrow[r], d);
        }
    }
    #pragma unroll
    for (int r = 0; r < 4; ++r)
        #pragma unroll
        for (int m = 8; m >= 1; m >>= 1)
            mrow[r] = fmaxf(mrow[r], __shfl_xor(mrow[r], m, 64));
    float srow[4] = {0.f, 0.f, 0.f, 0.f};
    #pragma unroll
    for (int kt = 0; kt < 8; ++kt)
        #pragma unroll
        for (int r = 0; r < 4; ++r)
            srow[r] += __expf(dacc[kt][r] - mrow[r]);
    #pragma unroll
    for (int r = 0; r < 4; ++r)
        #pragma unroll
        for (int m = 8; m >= 1; m >>= 1)
            srow[r] += __shfl_xor(srow[r], m, 64);
    float lse[4];
    #pragma unroll
    for (int r = 0; r < 4; ++r) lse[r] = mrow[r] + __logf(srow[r]);
    if (cc == 0){
        #pragma unroll
        for (int r = 0; r < 4; ++r) s_lse[w * 16 + quad * 4 + r] = lse[r];
    }

    // ---- probs -> sP (C-layout scatter into swizzled A-layout tile) ----
    #pragma unroll
    for (int kt = 0; kt < 8; ++kt){
        int kk = kt * 16 + cc;
        #pragma unroll
        for (int r = 0; r < 4; ++r){
            int q = w * 16 + quad * 4 + r;
            sP[q * 128 + (((kk >> 3) ^ (q & 15)) * 8) + (kk & 7)] =
                f2bf(__expf(dacc[kt][r] - lse[r]));
        }
    }
    __syncthreads();

    // ---- PV: wave w -> q-tile w; 4 k-chunks x 4 n-tiles ----
    f32x4 oacc[4];
    #pragma unroll
    for (int j = 0; j < 4; ++j) oacc[j] = (f32x4){0.f, 0.f, 0.f, 0.f};
    #pragma unroll
    for (int kc = 0; kc < 4; ++kc){
        short8 afrag = *(const short8*)&sP[qrow * 128 + (((kc * 4 + quad) ^ cc) * 8)];
        #pragma unroll
        for (int nt = 0; nt < 4; ++nt){
            int d = nt * 16 + cc;
            short8 bfrag = *(const short8*)&sVt[d * 128 + (((kc * 4 + quad) ^ cc) * 8)];
            oacc[nt] = __builtin_amdgcn_mfma_f32_16x16x32_bf16(afrag, bfrag, oacc[nt], 0, 0, 0);
        }
    }

    // ---- epilogue: scatter o (bf16) and logits to per-hash buffers ----
    #pragma unroll
    for (int r = 0; r < 4; ++r){
        int q = w * 16 + quad * 4 + r;
        int si = s_idx[q];
        int jj = si >> 12; int t = si & (T_ - 1);
        size_t base = ((size_t)(hn * NH_ + jj) * T_ + t) * 64;
        #pragma unroll
        for (int nt = 0; nt < 4; ++nt)
            o_hash[base + nt * 16 + cc] = f2bf(oacc[nt][r]);
    }
    if (tid < 64){
        int si = s_idx[tid]; int jj = si >> 12; int t = si & (T_ - 1);
        logit_hash[(size_t)(hn * NH_ + jj) * T_ + t] = s_lse[tid];
    }
}

// ---------------------------------------------------------------------------
// K5: combine over NH hash rounds per head + fused LayerNorm. block = (t,n)
// ---------------------------------------------------------------------------
__global__ __launch_bounds__(256) void k_comb(const u16* __restrict__ o_hash,
        const float* __restrict__ logit_hash, const float* __restrict__ gamma,
        const float* __restrict__ beta, float* __restrict__ out){
    const int t = blockIdx.x, n = blockIdx.y;
    const int tid = threadIdx.x;
    __shared__ float s_pw[32];
    __shared__ float s_x[512];
    __shared__ float s_red[8];
    __shared__ float s_mu, s_rs;
    if (tid < 32){
        int h = tid >> 2, j = tid & 3;
        s_pw[tid] = logit_hash[(size_t)((h * N_ + n) * NH_ + j) * T_ + t];
    }
    __syncthreads();
    if (tid < 8){
        int h = tid;
        float m = -1e30f;
        #pragma unroll
        for (int j = 0; j < 4; ++j) m = fmaxf(m, s_pw[h * 4 + j]);
        float l = 0.f;
        #pragma unroll
        for (int j = 0; j < 4; ++j) l += __expf(s_pw[h * 4 + j] - m);
        float ls = m + __logf(l);
        #pragma unroll
        for (int j = 0; j < 4; ++j) s_pw[h * 4 + j] = __expf(s_pw[h * 4 + j] - ls);
    }
    __syncthreads();
    float va[2];
    #pragma unroll
    for (int i = 0; i < 2; ++i){
        int cidx = tid + i * 256;
        int h = cidx >> 6, d = cidx & 63;
        size_t base = (size_t)((h * N_ + n) * NH_) * T_ * 64;
        float acc = 0.f;
        #pragma unroll
        for (int j = 0; j < 4; ++j)
            acc += s_pw[h * 4 + j] * bf2f(o_hash[base + ((size_t)j * T_ + t) * 64 + d]);
        s_x[cidx] = acc; va[i] = acc;
    }
    float s1 = va[0] + va[1];
    float s2 = va[0] * va[0] + va[1] * va[1];
    #pragma unroll
    for (int m = 32; m >= 1; m >>= 1){
        s1 += __shfl_xor(s1, m, 64);
        s2 += __shfl_xor(s2, m, 64);
    }
    const int lane = tid & 63, w = tid >> 6;
    if (lane == 0){ s_red[w] = s1; s_red[4 + w] = s2; }
    __syncthreads();
    if (tid == 0){
        float S1 = s_red[0] + s_red[1] + s_red[2] + s_red[3];
        float S2 = s_red[4] + s_red[5] + s_red[6] + s_red[7];
        float mu = S1 / 512.f;
        float var = S2 / 512.f - mu * mu;
        s_mu = mu; s_rs = 1.f / sqrtf(var + 1e-3f);
    }
    __syncthreads();
    #pragma unroll
    for (int i = 0; i < 2; ++i){
        int cidx = tid + i * 256;
        out[((size_t)(n * T_ + t)) * 512 + cidx] =
            gamma[cidx] * (s_x[cidx] - s_mu) * s_rs + beta[cidx];
    }
}

// ---------------------------------------------------------------------------
extern "C" void kernel_launch(void* const* d_in, const int* in_sizes, int n_in,
                              void* d_out, int out_size, void* d_ws, size_t ws_size,
                              hipStream_t stream){
    const float* x     = (const float*)d_in[0];
    const float* Wq    = (const float*)d_in[1];
    const float* bq    = (const float*)d_in[2];
    const float* Wv    = (const float*)d_in[3];
    const float* bv    = (const float*)d_in[4];
    const float* gamma = (const float*)d_in[5];
    const float* beta  = (const float*)d_in[6];
    const float* rot   = (const float*)d_in[7];
    char* ws = (char*)d_ws;
    // workspace layout (total ~140.5 MB)
    float* Q        = (float*)(ws + 0);               // 33,554,432 B
    float* V        = (float*)(ws + 33554432);        // 33,554,432 B
    int*   buckets  = (int*)  (ws + 67108864);        //  2,097,152 B
    int*   sticker  = (int*)  (ws + 69206016);        //  2,097,152 B
    float* logit    = (float*)(ws + 71303168);        //  2,097,152 B
    u16*   o_hash   = (u16*)  (ws + 73400320);        // 67,108,864 B
    // scratch overlapping o_hash (dead before k_attn writes o_hash;
    // same-stream program order guarantees safety):
    u16*   xf       = (u16*)  (ws + 73400320);        // 16,777,216 B
    u16*   wvt      = (u16*)  (ws + 90177536);        //    524,288 B
    int*   hist     = (int*)  (ws + 73400320);        //  2,097,152 B (after k_gemmV)
    int*   bstart   = (int*)  (ws + 75497472);        //     32,768 B

    hipLaunchKernelGGL(k_decXf,   dim3(8192),       dim3(256), 0, stream,
                       x, xf);
    hipLaunchKernelGGL(k_decWv,   dim3(16, 16),     dim3(256), 0, stream,
                       Wv, wvt);
    hipLaunchKernelGGL(k_gemmV,   dim3(128, 4),     dim3(256), 0, stream,
                       xf, wvt, bv, V);
    hipLaunchKernelGGL(k_q,       dim3(128, 8),     dim3(256), 0, stream,
                       x, Wq, bq, Q);
    hipLaunchKernelGGL(k_rot,     dim3(128, 4, 8),  dim3(256), 0, stream,
                       Q, rot, buckets);
    hipLaunchKernelGGL(k_hist,    dim3(64, 32),     dim3(256), 0, stream,
                       buckets, hist);
    hipLaunchKernelGGL(k_scan,    dim3(32),         dim3(256), 0, stream,
                       hist, bstart);
    hipLaunchKernelGGL(k_scatter, dim3(64, 32),     dim3(256), 0, stream,
                       buckets, hist, bstart, sticker);
    hipLaunchKernelGGL(k_attn,    dim3(256, 4, 8),  dim3(256), 0, stream,
                       Q, V, buckets, sticker, o_hash, logit);
    hipLaunchKernelGGL(k_comb,    dim3(4096, 4),    dim3(256), 0, stream,
                       o_hash, logit, gamma, beta, (float*)d_out);
}

// Round 6
// 427.634 us; speedup vs baseline: 4.6706x; 1.0730x over previous
//
#include <hip/hip_runtime.h>
#include <hip/hip_bf16.h>

#define N_ 4
#define T_ 4096
#define D_ 512
#define H_ 8
#define DH_ 64
#define NH_ 4
#define NB_ 64
#define CS_ 256
#define L_ 16384

typedef unsigned short u16;
typedef unsigned int u32;
typedef __attribute__((ext_vector_type(8))) short short8;
typedef __attribute__((ext_vector_type(8))) _Float16 half8;
typedef __attribute__((ext_vector_type(4))) float f32x4;

__device__ __forceinline__ u16 f2bf(float x){
    union { float f; u32 u; } c; c.f = x;
    u32 u = c.u;
    u32 r = (u + 0x7FFFu + ((u >> 16) & 1u)) >> 16;
    return (u16)r;
}
__device__ __forceinline__ float bf2f(u16 b){
    union { u32 u; float f; } c; c.u = ((u32)b) << 16;
    return c.f;
}
__device__ __forceinline__ u16 f2h(float x){
    _Float16 h = (_Float16)x;
    u16 r; __builtin_memcpy(&r, &h, 2); return r;
}

// ---------------------------------------------------------------------------
// K0a: x -> f16 copy (for V MFMA path)
// ---------------------------------------------------------------------------
__global__ __launch_bounds__(256) void k_decXf(const float* __restrict__ x,
        u16* __restrict__ xf){
    int i = blockIdx.x * 256 + threadIdx.x;        // float4 index
    float4 v = ((const float4*)x)[i];
    ushort4 o;
    o.x = f2h(v.x); o.y = f2h(v.y); o.z = f2h(v.z); o.w = f2h(v.w);
    ((ushort4*)xf)[i] = o;
}

// ---------------------------------------------------------------------------
// K0b: transpose Wv -> wvt [512 n][512 k] f16
// ---------------------------------------------------------------------------
__global__ __launch_bounds__(256) void k_decWv(const float* __restrict__ Wv,
        u16* __restrict__ wvt){
    __shared__ float tile[32][33];
    const int tid = threadIdx.x;
    const int kt = blockIdx.x * 32, nt = blockIdx.y * 32;
    const int tx = tid & 31, ty = tid >> 5;
    #pragma unroll
    for (int i = 0; i < 4; ++i)
        tile[ty + i * 8][tx] = Wv[(size_t)(kt + ty + i * 8) * 512 + nt + tx];
    __syncthreads();
    #pragma unroll
    for (int i = 0; i < 4; ++i){
        int n = ty + i * 8;
        wvt[(size_t)(nt + n) * 512 + kt + tx] = f2h(tile[tx][n]);
    }
}

// ---------------------------------------------------------------------------
// K1a: Q = x@W_Q + b_Q  (fp32 VALU — exact-class for bucket argmax).
//      Also emits Qbf (bf16 head-major) + qinv row norms for k_attn.
// ---------------------------------------------------------------------------
__global__ __launch_bounds__(256) void k_q(const float* __restrict__ x,
        const float* __restrict__ Wq, const float* __restrict__ bq,
        float* __restrict__ Q, u16* __restrict__ Qbf, float* __restrict__ qinv){
    __shared__ float sA[16][132];     // [k][m] transposed, pad 132
    __shared__ float sB[16][68];      // [k][n]
    const int tid = threadIdx.x;
    const int tx = tid & 15, ty = tid >> 4;
    const int mb = blockIdx.x * 128, nb = blockIdx.y * 64;
    const int h = blockIdx.y;                       // head = column block
    float acc[8][4] = {};
    for (int k0 = 0; k0 < 512; k0 += 16){
        #pragma unroll
        for (int i = 0; i < 2; ++i){
            int idx = i * 256 + tid;               // 0..511
            int m = idx >> 2, kq = idx & 3;
            float4 v = *(const float4*)&x[(size_t)(mb + m) * 512 + k0 + kq * 4];
            sA[kq * 4 + 0][m] = v.x;
            sA[kq * 4 + 1][m] = v.y;
            sA[kq * 4 + 2][m] = v.z;
            sA[kq * 4 + 3][m] = v.w;
        }
        {
            int kk = tid >> 4, nq = tid & 15;
            *(float4*)&sB[kk][nq * 4] =
                *(const float4*)&Wq[(size_t)(k0 + kk) * 512 + nb + nq * 4];
        }
        __syncthreads();
        #pragma unroll
        for (int kk = 0; kk < 16; ++kk){
            float a[8], b[4];
            *(float4*)&a[0] = *(const float4*)&sA[kk][ty * 8];
            *(float4*)&a[4] = *(const float4*)&sA[kk][ty * 8 + 4];
            *(float4*)&b[0] = *(const float4*)&sB[kk][tx * 4];
            #pragma unroll
            for (int i = 0; i < 8; ++i)
                #pragma unroll
                for (int j = 0; j < 4; ++j) acc[i][j] += a[i] * b[j];
        }
        __syncthreads();
    }
    float4 bi = *(const float4*)&bq[nb + tx * 4];
    #pragma unroll
    for (int i = 0; i < 8; ++i){
        float o0 = acc[i][0] + bi.x, o1 = acc[i][1] + bi.y;
        float o2 = acc[i][2] + bi.z, o3 = acc[i][3] + bi.w;
        int m = mb + ty * 8 + i;
        float4 o4; o4.x = o0; o4.y = o1; o4.z = o2; o4.w = o3;
        *(float4*)&Q[(size_t)m * 512 + nb + tx * 4] = o4;
        float ss = o0 * o0 + o1 * o1 + o2 * o2 + o3 * o3;
        #pragma unroll
        for (int s = 8; s >= 1; s >>= 1) ss += __shfl_xor(ss, s, 64);
        int n = m >> 12, t = m & (T_ - 1);
        size_t rowb = (size_t)(h * N_ + n) * T_ + t;
        if (tx == 0) qinv[rowb] = 1.f / (sqrtf(ss) + 1e-6f);
        ushort4 ob;
        ob.x = f2bf(o0); ob.y = f2bf(o1); ob.z = f2bf(o2); ob.w = f2bf(o3);
        *(ushort4*)&Qbf[rowb * 64 + tx * 4] = ob;
    }
}

// ---------------------------------------------------------------------------
// K1b: V = x@W_V + b_V  via single-product f16 MFMA -> Vbf bf16 head-major.
// ---------------------------------------------------------------------------
__global__ __launch_bounds__(256) void k_gemmV(const u16* __restrict__ xf,
        const u16* __restrict__ wvt, const float* __restrict__ bv,
        u16* __restrict__ Vbf){
    __shared__ __align__(16) u16 sA[128 * 40];
    __shared__ __align__(16) u16 sB[128 * 40];
    const int tid = threadIdx.x;
    const int mb = blockIdx.x * 128, nb = blockIdx.y * 128;
    const int w = tid >> 6, lane = tid & 63, quad = lane >> 4, cc = lane & 15;
    const int wm = (w & 1) * 64, wn = (w >> 1) * 64;
    f32x4 acc[4][4];
    #pragma unroll
    for (int i = 0; i < 4; ++i)
        #pragma unroll
        for (int j = 0; j < 4; ++j) acc[i][j] = (f32x4){0.f, 0.f, 0.f, 0.f};

    for (int k0 = 0; k0 < 512; k0 += 32){
        #pragma unroll
        for (int i = 0; i < 2; ++i){
            int idx = i * 256 + tid;               // 0..511
            int m = idx >> 2, ks = idx & 3;
            *(short8*)&sA[m * 40 + ks * 8] =
                *(const short8*)&xf[(size_t)(mb + m) * 512 + k0 + ks * 8];
            *(short8*)&sB[m * 40 + ks * 8] =
                *(const short8*)&wvt[(size_t)(nb + m) * 512 + k0 + ks * 8];
        }
        __syncthreads();
        half8 a[4], b[4];
        #pragma unroll
        for (int i = 0; i < 4; ++i){
            a[i] = *(const half8*)&sA[(wm + i * 16 + cc) * 40 + quad * 8];
            b[i] = *(const half8*)&sB[(wn + i * 16 + cc) * 40 + quad * 8];
        }
        #pragma unroll
        for (int i = 0; i < 4; ++i)
            #pragma unroll
            for (int j = 0; j < 4; ++j)
                acc[i][j] = __builtin_amdgcn_mfma_f32_16x16x32_f16(a[i], b[j], acc[i][j], 0, 0, 0);
        __syncthreads();
    }
    #pragma unroll
    for (int i = 0; i < 4; ++i)
        #pragma unroll
        for (int j = 0; j < 4; ++j){
            int c = nb + wn + j * 16 + cc;
            int hh = c >> 6, d = c & 63;
            float bi = bv[c];
            #pragma unroll
            for (int r = 0; r < 4; ++r){
                int m = mb + wm + i * 16 + quad * 4 + r;
                int n = m >> 12, t = m & (T_ - 1);
                Vbf[((size_t)(hh * N_ + n) * T_ + t) * 64 + d] = f2bf(acc[i][j][r] + bi);
            }
        }
}

// ---------------------------------------------------------------------------
// K2: rotations + argmax -> buckets[h][n][j*T + t]  (fp32, exact tie rules)
// ---------------------------------------------------------------------------
__global__ __launch_bounds__(256) void k_rot(const float* __restrict__ Q,
        const float* __restrict__ rot, int* __restrict__ buckets){
    const int tb = blockIdx.x * 32;
    const int n = blockIdx.y, h = blockIdx.z;
    const int hn = h * N_ + n;
    __shared__ float Rs[64 * 128];
    __shared__ float Qs[32][64];
    const int tid = threadIdx.x;
    const float* rh = rot + (size_t)h * (64 * 128);   // [f][j][i] contiguous
    for (int i = tid; i < 8192; i += 256) Rs[i] = rh[i];
    for (int i = tid; i < 2048; i += 256){
        int t = i >> 6, f = i & 63;
        Qs[t][f] = Q[(size_t)(n * T_ + tb + t) * 512 + h * 64 + f];
    }
    __syncthreads();
    const int tx = tid & 31, tg = tid >> 5;   // tg: 8 groups of 4 t's
    float r[4][4] = {};
    for (int f = 0; f < 64; ++f){
        float q0 = Qs[tg * 4 + 0][f], q1 = Qs[tg * 4 + 1][f];
        float q2 = Qs[tg * 4 + 2][f], q3 = Qs[tg * 4 + 3][f];
        #pragma unroll
        for (int jj = 0; jj < 4; ++jj){
            float rv = Rs[f * 128 + jj * 32 + tx];
            r[0][jj] += q0 * rv; r[1][jj] += q1 * rv;
            r[2][jj] += q2 * rv; r[3][jj] += q3 * rv;
        }
    }
    #pragma unroll
    for (int tt = 0; tt < 4; ++tt){
        #pragma unroll
        for (int jj = 0; jj < 4; ++jj){
            // argmax over concat(r, -r); first-occurrence tie-break
            float bv = r[tt][jj]; int bi = tx;
            float nv = -bv;
            if (nv > bv){ bv = nv; bi = 32 + tx; }
            #pragma unroll
            for (int m = 16; m >= 1; m >>= 1){
                float ov = __shfl_xor(bv, m, 32);
                int   oi = __shfl_xor(bi, m, 32);
                if (ov > bv || (ov == bv && oi < bi)){ bv = ov; bi = oi; }
            }
            if (tx == 0){
                int t = tb + tg * 4 + tt;
                buckets[(size_t)hn * L_ + jj * T_ + t] = bi + jj * 64;
            }
        }
    }
}

// ---------------------------------------------------------------------------
// K3a: per-(hn,tile) 256-bin histogram. tile = 256 consecutive items.
// ---------------------------------------------------------------------------
__global__ __launch_bounds__(256) void k_hist(const int* __restrict__ buckets,
        int* __restrict__ hist){
    const int tile = blockIdx.x, hn = blockIdx.y;
    const int tid = threadIdx.x;
    __shared__ int h[256];
    h[tid] = 0;
    __syncthreads();
    int b = buckets[(size_t)hn * L_ + tile * 256 + tid];
    atomicAdd(&h[b], 1);
    __syncthreads();
    hist[((size_t)hn * 64 + tile) * 256 + tid] = h[tid];
}

// ---------------------------------------------------------------------------
// K3b: per-hn: in-place exclusive prefix of hist over tiles (per bucket),
//      then block scan of bucket totals -> bucketStart[hn][256]
// ---------------------------------------------------------------------------
__global__ __launch_bounds__(256) void k_scan(int* __restrict__ hist,
        int* __restrict__ bucketStart){
    const int hn = blockIdx.x;
    const int b = threadIdx.x;
    int* hh = hist + (size_t)hn * 64 * 256;
    int run = 0;
    for (int tl = 0; tl < 64; ++tl){
        int v = hh[tl * 256 + b];
        hh[tl * 256 + b] = run;      // exclusive within-bucket tile prefix
        run += v;
    }
    __shared__ int s[256];
    s[b] = run;
    __syncthreads();
    for (int off = 1; off < 256; off <<= 1){
        int add = (b >= off) ? s[b - off] : 0;
        __syncthreads();
        s[b] += add;
        __syncthreads();
    }
    bucketStart[hn * 256 + b] = s[b] - run;   // exclusive bucket start
}

// ---------------------------------------------------------------------------
// K3c: stable scatter: sticker[pos] = item index
// ---------------------------------------------------------------------------
__global__ __launch_bounds__(256) void k_scatter(const int* __restrict__ buckets,
        const int* __restrict__ offs, const int* __restrict__ bucketStart,
        int* __restrict__ sticker){
    const int tile = blockIdx.x, hn = blockIdx.y;
    const int tid = threadIdx.x;
    __shared__ int sb[256];
    const int i = tile * 256 + tid;
    const int b = buckets[(size_t)hn * L_ + i];
    sb[tid] = b;
    __syncthreads();
    int rank = 0;
    #pragma unroll 8
    for (int j = 0; j < 256; ++j){
        int v = sb[j];                         // broadcast read
        rank += (j < tid && v == b) ? 1 : 0;
    }
    int pos = bucketStart[hn * 256 + b]
            + offs[((size_t)hn * 64 + tile) * 256 + b]
            + rank;
    sticker[(size_t)hn * L_ + pos] = i;
}

// ---------------------------------------------------------------------------
// K4: chunked attention via MFMA. block = (chunk, n, h). 64 q x 128 k, DH=64
//     Staging from pre-converted bf16 Qbf/Vbf + precomputed qinv.
// ---------------------------------------------------------------------------
__global__ __launch_bounds__(256) void k_attn(const u16* __restrict__ Qbf,
        const u16* __restrict__ Vbf, const float* __restrict__ qinv,
        const int* __restrict__ buckets, const int* __restrict__ sticker,
        u16* __restrict__ o_hash, float* __restrict__ logit_hash){
    const int blk_c = blockIdx.x, n = blockIdx.y, h = blockIdx.z;
    const int hn = h * N_ + n;
    const int tid = threadIdx.x;
    const int w = tid >> 6, lane = tid & 63;
    const int quad = lane >> 4, cc = lane & 15;

    // XOR-swizzled bf16 tiles: element (r,c) of a 64-col tile lives at
    //   r*64 + ((c>>3)^(r&7))*8 + (c&7); 128-col tile uses ^(r&15).
    __shared__ __align__(16) u16 sQ[128 * 64];    // rows = sorted positions
    __shared__ __align__(16) u16 sVt[64 * 128];   // row = d, col = key row (V^T)
    __shared__ __align__(16) u16 sP[64 * 128];    // probs, row = q, col = k
    __shared__ int s_idx[128], s_buck[128], s_t[128];
    __shared__ float s_inv[128];
    __shared__ float s_lse[64];

    if (tid < 128){
        int cprev = (blk_c + CS_ - 1) & (CS_ - 1);
        int pos = (tid < 64) ? blk_c * 64 + tid : cprev * 64 + (tid - 64);
        int idx = sticker[(size_t)hn * L_ + pos];
        s_idx[tid] = idx;
        s_buck[tid] = buckets[(size_t)hn * L_ + idx];
        int t = idx & (T_ - 1);
        s_t[tid] = t;
        s_inv[tid] = qinv[(size_t)hn * T_ + t];
    }
    __syncthreads();

    // ---- stage Q rows (b128) and V transposed (scalar b16) ----
    const int r0 = tid >> 3, l8 = tid & 7;
    #pragma unroll
    for (int it = 0; it < 4; ++it){
        int r = it * 32 + r0;
        size_t gb = ((size_t)hn * T_ + s_t[r]) * 64 + l8 * 8;
        short8 qv = *(const short8*)&Qbf[gb];
        *(short8*)&sQ[r * 64 + ((l8 ^ (r & 7)) * 8)] = qv;
        short8 vv = *(const short8*)&Vbf[gb];
        #pragma unroll
        for (int i = 0; i < 8; ++i){
            int d = l8 * 8 + i;
            sVt[d * 128 + (((r >> 3) ^ (d & 15)) * 8) + (r & 7)] = (u16)vv[i];
        }
    }
    __syncthreads();

    // ---- QK^T: wave w -> q-tile w; 2 k-chunks x 8 k-tiles ----
    f32x4 dacc[8];
    #pragma unroll
    for (int j = 0; j < 8; ++j) dacc[j] = (f32x4){0.f, 0.f, 0.f, 0.f};
    const int qrow = w * 16 + cc;
    #pragma unroll
    for (int kc = 0; kc < 2; ++kc){
        short8 afrag = *(const short8*)&sQ[qrow * 64 + (((kc * 4 + quad) ^ (cc & 7)) * 8)];
        #pragma unroll
        for (int kt = 0; kt < 8; ++kt){
            int krow = kt * 16 + cc;
            short8 bfrag = *(const short8*)&sQ[krow * 64 + (((kc * 4 + quad) ^ (cc & 7)) * 8)];
            dacc[kt] = __builtin_amdgcn_mfma_f32_16x16x32_bf16(afrag, bfrag, dacc[kt], 0, 0, 0);
        }
    }

    // ---- scale + masks + row softmax (rows: q = w*16 + quad*4 + reg) ----
    int bq[4], tq[4];
    #pragma unroll
    for (int r = 0; r < 4; ++r){
        int q = w * 16 + quad * 4 + r;
        bq[r] = s_buck[q]; tq[r] = s_t[q];
    }
    float mrow[4] = {-1e30f, -1e30f, -1e30f, -1e30f};
    #pragma unroll
    for (int kt = 0; kt < 8; ++kt){
        int kk = kt * 16 + cc;
        float inv = s_inv[kk] * 0.125f;
        int bk = s_buck[kk], tk = s_t[kk];
        #pragma unroll
        for (int r = 0; r < 4; ++r){
            float d = dacc[kt][r] * inv;
            if (bk != bq[r]) d = -1e9f;
            if (tk == tq[r]) d = -1e-5f;
            dacc[kt][r] = d;
            mrow[r] = fmaxf(mrow[r], d);
        }
    }
    #pragma unroll
    for (int r = 0; r < 4; ++r)
        #pragma unroll
        for (int m = 8; m >= 1; m >>= 1)
            mrow[r] = fmaxf(mrow[r], __shfl_xor(mrow[r], m, 64));
    // exp once: keep p = exp(d - m) in dacc, sum it
    float srow[4] = {0.f, 0.f, 0.f, 0.f};
    #pragma unroll
    for (int kt = 0; kt < 8; ++kt)
        #pragma unroll
        for (int r = 0; r < 4; ++r){
            float e = __expf(dacc[kt][r] - mrow[r]);
            dacc[kt][r] = e;
            srow[r] += e;
        }
    #pragma unroll
    for (int r = 0; r < 4; ++r)
        #pragma unroll
        for (int m = 8; m >= 1; m >>= 1)
            srow[r] += __shfl_xor(srow[r], m, 64);
    float lse[4], pscale[4];
    #pragma unroll
    for (int r = 0; r < 4; ++r){
        lse[r] = mrow[r] + __logf(srow[r]);
        pscale[r] = 1.f / srow[r];
    }
    if (cc == 0){
        #pragma unroll
        for (int r = 0; r < 4; ++r) s_lse[w * 16 + quad * 4 + r] = lse[r];
    }

    // ---- probs -> sP (C-layout scatter into swizzled A-layout tile) ----
    #pragma unroll
    for (int kt = 0; kt < 8; ++kt){
        int kk = kt * 16 + cc;
        #pragma unroll
        for (int r = 0; r < 4; ++r){
            int q = w * 16 + quad * 4 + r;
            sP[q * 128 + (((kk >> 3) ^ (q & 15)) * 8) + (kk & 7)] =
                f2bf(dacc[kt][r] * pscale[r]);
        }
    }
    __syncthreads();

    // ---- PV: wave w -> q-tile w; 4 k-chunks x 4 n-tiles ----
    f32x4 oacc[4];
    #pragma unroll
    for (int j = 0; j < 4; ++j) oacc[j] = (f32x4){0.f, 0.f, 0.f, 0.f};
    #pragma unroll
    for (int kc = 0; kc < 4; ++kc){
        short8 afrag = *(const short8*)&sP[qrow * 128 + (((kc * 4 + quad) ^ cc) * 8)];
        #pragma unroll
        for (int nt = 0; nt < 4; ++nt){
            int d = nt * 16 + cc;
            short8 bfrag = *(const short8*)&sVt[d * 128 + (((kc * 4 + quad) ^ cc) * 8)];
            oacc[nt] = __builtin_amdgcn_mfma_f32_16x16x32_bf16(afrag, bfrag, oacc[nt], 0, 0, 0);
        }
    }

    // ---- epilogue: scatter o (bf16) and logits to per-hash buffers ----
    #pragma unroll
    for (int r = 0; r < 4; ++r){
        int q = w * 16 + quad * 4 + r;
        int si = s_idx[q];
        int jj = si >> 12; int t = si & (T_ - 1);
        size_t base = ((size_t)(hn * NH_ + jj) * T_ + t) * 64;
        #pragma unroll
        for (int nt = 0; nt < 4; ++nt)
            o_hash[base + nt * 16 + cc] = f2bf(oacc[nt][r]);
    }
    if (tid < 64){
        int si = s_idx[tid]; int jj = si >> 12; int t = si & (T_ - 1);
        logit_hash[(size_t)(hn * NH_ + jj) * T_ + t] = s_lse[tid];
    }
}

// ---------------------------------------------------------------------------
// K5: combine over NH hash rounds per head + fused LayerNorm. block = (t,n)
// ---------------------------------------------------------------------------
__global__ __launch_bounds__(256) void k_comb(const u16* __restrict__ o_hash,
        const float* __restrict__ logit_hash, const float* __restrict__ gamma,
        const float* __restrict__ beta, float* __restrict__ out){
    const int t = blockIdx.x, n = blockIdx.y;
    const int tid = threadIdx.x;
    __shared__ float s_pw[32];
    __shared__ float s_x[512];
    __shared__ float s_red[8];
    __shared__ float s_mu, s_rs;
    if (tid < 32){
        int h = tid >> 2, j = tid & 3;
        s_pw[tid] = logit_hash[(size_t)((h * N_ + n) * NH_ + j) * T_ + t];
    }
    __syncthreads();
    if (tid < 8){
        int h = tid;
        float m = -1e30f;
        #pragma unroll
        for (int j = 0; j < 4; ++j) m = fmaxf(m, s_pw[h * 4 + j]);
        float l = 0.f;
        #pragma unroll
        for (int j = 0; j < 4; ++j) l += __expf(s_pw[h * 4 + j] - m);
        float ls = m + __logf(l);
        #pragma unroll
        for (int j = 0; j < 4; ++j) s_pw[h * 4 + j] = __expf(s_pw[h * 4 + j] - ls);
    }
    __syncthreads();
    float va[2];
    #pragma unroll
    for (int i = 0; i < 2; ++i){
        int cidx = tid + i * 256;
        int h = cidx >> 6, d = cidx & 63;
        size_t base = (size_t)((h * N_ + n) * NH_) * T_ * 64;
        float acc = 0.f;
        #pragma unroll
        for (int j = 0; j < 4; ++j)
            acc += s_pw[h * 4 + j] * bf2f(o_hash[base + ((size_t)j * T_ + t) * 64 + d]);
        s_x[cidx] = acc; va[i] = acc;
    }
    float s1 = va[0] + va[1];
    float s2 = va[0] * va[0] + va[1] * va[1];
    #pragma unroll
    for (int m = 32; m >= 1; m >>= 1){
        s1 += __shfl_xor(s1, m, 64);
        s2 += __shfl_xor(s2, m, 64);
    }
    const int lane = tid & 63, w = tid >> 6;
    if (lane == 0){ s_red[w] = s1; s_red[4 + w] = s2; }
    __syncthreads();
    if (tid == 0){
        float S1 = s_red[0] + s_red[1] + s_red[2] + s_red[3];
        float S2 = s_red[4] + s_red[5] + s_red[6] + s_red[7];
        float mu = S1 / 512.f;
        float var = S2 / 512.f - mu * mu;
        s_mu = mu; s_rs = 1.f / sqrtf(var + 1e-3f);
    }
    __syncthreads();
    #pragma unroll
    for (int i = 0; i < 2; ++i){
        int cidx = tid + i * 256;
        out[((size_t)(n * T_ + t)) * 512 + cidx] =
            gamma[cidx] * (s_x[cidx] - s_mu) * s_rs + beta[cidx];
    }
}

// ---------------------------------------------------------------------------
extern "C" void kernel_launch(void* const* d_in, const int* in_sizes, int n_in,
                              void* d_out, int out_size, void* d_ws, size_t ws_size,
                              hipStream_t stream){
    const float* x     = (const float*)d_in[0];
    const float* Wq    = (const float*)d_in[1];
    const float* bq    = (const float*)d_in[2];
    const float* Wv    = (const float*)d_in[3];
    const float* bv    = (const float*)d_in[4];
    const float* gamma = (const float*)d_in[5];
    const float* beta  = (const float*)d_in[6];
    const float* rot   = (const float*)d_in[7];
    char* ws = (char*)d_ws;
    // workspace layout (<= ~140.5 MB). Time-disjoint overlap:
    //   Q fp32 [0,33.5MB) is dead after k_rot; o_hash [0,67.1MB) is written
    //   only by k_attn (strictly later in stream order).
    float* Q        = (float*)(ws + 0);               // 33,554,432 B (k_q..k_rot)
    u16*   o_hash   = (u16*)  (ws + 0);               // 67,108,864 B (k_attn..k_comb)
    u16*   Qbf      = (u16*)  (ws + 67108864);        // 16,777,216 B
    u16*   Vbf      = (u16*)  (ws + 83886080);        // 16,777,216 B
    float* qinv     = (float*)(ws + 100663296);       //    524,288 B
    int*   buckets  = (int*)  (ws + 101187584);       //  2,097,152 B
    int*   sticker  = (int*)  (ws + 103284736);       //  2,097,152 B
    float* logit    = (float*)(ws + 105381888);       //  2,097,152 B
    int*   hist     = (int*)  (ws + 107479040);       //  2,097,152 B
    int*   bstart   = (int*)  (ws + 109576192);       //     32,768 B
    u16*   xf       = (u16*)  (ws + 109608960);       // 16,777,216 B (dead after k_gemmV)
    u16*   wvt      = (u16*)  (ws + 126386176);       //    524,288 B

    hipLaunchKernelGGL(k_decXf,   dim3(8192),       dim3(256), 0, stream,
                       x, xf);
    hipLaunchKernelGGL(k_decWv,   dim3(16, 16),     dim3(256), 0, stream,
                       Wv, wvt);
    hipLaunchKernelGGL(k_gemmV,   dim3(128, 4),     dim3(256), 0, stream,
                       xf, wvt, bv, Vbf);
    hipLaunchKernelGGL(k_q,       dim3(128, 8),     dim3(256), 0, stream,
                       x, Wq, bq, Q, Qbf, qinv);
    hipLaunchKernelGGL(k_rot,     dim3(128, 4, 8),  dim3(256), 0, stream,
                       Q, rot, buckets);
    hipLaunchKernelGGL(k_hist,    dim3(64, 32),     dim3(256), 0, stream,
                       buckets, hist);
    hipLaunchKernelGGL(k_scan,    dim3(32),         dim3(256), 0, stream,
                       hist, bstart);
    hipLaunchKernelGGL(k_scatter, dim3(64, 32),     dim3(256), 0, stream,
                       buckets, hist, bstart, sticker);
    hipLaunchKernelGGL(k_attn,    dim3(256, 4, 8),  dim3(256), 0, stream,
                       Qbf, Vbf, qinv, buckets, sticker, o_hash, logit);
    hipLaunchKernelGGL(k_comb,    dim3(4096, 4),    dim3(256), 0, stream,
                       o_hash, logit, gamma, beta, (float*)d_out);
}